// Round 8
// baseline (182.852 us; speedup 1.0000x reference)
//
#include <hip/hip_runtime.h>
#include <hip/hip_bf16.h>
#include <stdint.h>

#define NROWS 16384
#define NDIM  1024
#define NLAB  64
#define NC    65
#define CPAD  80

typedef float float4v __attribute__((ext_vector_type(4)));
typedef short short8  __attribute__((ext_vector_type(8)));

// ---- workspace layout (bytes); nothing needs pre-zeroing ----
static constexpr size_t SCALE_B = 0;         // 80 f32
static constexpr size_t ACTB_B  = 320;       // 80 u8
static constexpr size_t WSUM_B  = 400;       // f32 loss accumulator (zeroed by kC)
static constexpr size_t DONE_B  = 404;       // u32 block-done counter (zeroed by kC)
static constexpr size_t CNTF_B  = 448;       // 80 u32 counts
static constexpr size_t CNTP_B  = 1024;      // 256 x 80 u32 count slabs
static constexpr size_t MASK_B  = 83968;     // 16384 u64 row masks
static constexpr size_t LFRAG_B = 280576;    // labT bf16 A-frag (2.6 MB)
static constexpr size_t BFRAG_B = 2902016;   // unit anchors bf16 B-frag (160 KB)
static constexpr size_t XAF_B   = 3065856;   // x bf16 A-frag (32 MB)
static constexpr size_t PART_B  = 36620288;  // kslices*80*1024 f32 partials
static constexpr size_t SLAB    = (size_t)CPAD * NDIM * 4;

__device__ __forceinline__ unsigned short bf16u(float f) {
    __hip_bfloat16 h = __float2bfloat16(f);
    return __builtin_bit_cast(unsigned short, h);
}
__device__ __forceinline__ unsigned pk2(float a, float b) {
    return (unsigned)bf16u(a) | ((unsigned)bf16u(b) << 16);
}

// ---- kA: labels only; 256 blocks -> masks, cntpart, lfrag (verified) ----
__global__ __launch_bounds__(256) void kA_labels(const int* __restrict__ label,
                                                 unsigned long long* __restrict__ masks,
                                                 unsigned* __restrict__ cntpart,
                                                 unsigned short* __restrict__ lfrag) {
    __shared__ unsigned cnt[NC];
    __shared__ unsigned long long smask[64];
    int t = threadIdx.x;
    int bid = blockIdx.x;
    if (t < NC) cnt[t] = 0;
    __syncthreads();
    int wave = t >> 6, lane = t & 63;
    int rowblock = bid * 64;
    unsigned creg = 0, zreg = 0;
#pragma unroll 4
    for (int p = 0; p < 16; ++p) {
        int row = rowblock + p * 4 + wave;
        int v = label[row * NLAB + lane];
        unsigned long long m = __ballot(v != 0);
        creg += (unsigned)((m >> lane) & 1ull);
        if (lane == 0) {
            masks[row] = m;
            smask[p * 4 + wave] = m;
            zreg += (m == 0ull) ? 1u : 0u;
        }
    }
    atomicAdd(&cnt[lane], creg);
    if (lane == 0 && zreg) atomicAdd(&cnt[64], zreg);
    __syncthreads();
    if (t < 80) cntpart[bid * 80 + t] = (t < NC) ? cnt[t] : 0u;
    for (int pid = t; pid < 640; pid += 256) {
        int rt2l = pid / 320, rem = pid % 320;
        int ct = rem >> 6, ln = rem & 63;
        int qq = ln >> 4, cc = ln & 15;
        int c = ct * 16 + cc;
        int rbase = rt2l * 32 + qq * 8;
        unsigned pk[4];
#pragma unroll
        for (int jp = 0; jp < 4; ++jp) {
            unsigned long long m0 = smask[rbase + jp * 2], m1 = smask[rbase + jp * 2 + 1];
            unsigned b0, b1;
            if (c < 64)       { b0 = (unsigned)((m0 >> c) & 1ull); b1 = (unsigned)((m1 >> c) & 1ull); }
            else if (c == 64) { b0 = (m0 == 0ull); b1 = (m1 == 0ull); }
            else              { b0 = 0u; b1 = 0u; }
            pk[jp] = (b0 ? 0x3F80u : 0u) | (b1 ? 0x3F800000u : 0u);
        }
        uint4 w = make_uint4(pk[0], pk[1], pk[2], pk[3]);
        ((uint4*)lfrag)[((size_t)(bid * 2 + rt2l) * 5 + ct) * 64 + ln] = w;
    }
}

// ---- kG: anchor GEMM (labT @ x) + xAfrag emit from the SAME LDS-staged tile.
// x is read from HBM exactly once across the whole pipeline.
// grid = 16 * kslices (kslices=64 -> 1024 blocks, 4/CU) ----
__global__ __launch_bounds__(256) void kG(const float* __restrict__ x,
                                          const unsigned short* __restrict__ lfrag,
                                          float* __restrict__ partial,
                                          unsigned short* __restrict__ xAfrag,
                                          int kslices) {
    __shared__ float xt[2][32][65];
    int t = threadIdx.x, wave = t >> 6, lane = t & 63;
    int q = lane >> 4, col = lane & 15;
    int dgroup = blockIdx.x & 15, ks = blockIdx.x >> 4;
    int nkb = (NROWS / kslices) >> 5;
    int kb0 = ks * nkb;
    int d = dgroup * 64 + wave * 16 + col;
    const uint4* A = (const uint4*)lfrag;
    int srow = t >> 3, sd = (t & 7) * 8;

    // second-pass (xAfrag emit) thread mapping
    int rh = t >> 7;              // 0..1 : row half of the 32-row tile
    int kbh = (t >> 6) & 1;       // 0..1 : 32-dim half of the 64-dim slice
    int qq = (t >> 4) & 3;        // 0..3
    int cc = t & 15;              // 0..15
    int r2 = rh * 16 + cc;        // LDS row
    int dch = kbh * 4 + qq;       // 8-dim chunk within the 64-dim slice

    float4v acc[5];
#pragma unroll
    for (int ct = 0; ct < 5; ++ct) acc[ct] = (float4v){0.f, 0.f, 0.f, 0.f};

    {
        const float* g = x + ((size_t)(kb0 * 32 + srow)) * NDIM + dgroup * 64 + sd;
        float4 u = *(const float4*)g, v2 = *(const float4*)(g + 4);
        float* L = &xt[0][srow][sd];
        L[0] = u.x; L[1] = u.y; L[2] = u.z; L[3] = u.w;
        L[4] = v2.x; L[5] = v2.y; L[6] = v2.z; L[7] = v2.w;
    }
    __syncthreads();

    for (int i = 0; i < nkb; ++i) {
        int cur = i & 1;
        float4 u, v2;
        bool havenext = (i + 1) < nkb;
        if (havenext) {
            const float* g = x + ((size_t)((kb0 + i + 1) * 32 + srow)) * NDIM + dgroup * 64 + sd;
            u = *(const float4*)g; v2 = *(const float4*)(g + 4);
        }
        int kb = kb0 + i;
        uint4 a0[5];
#pragma unroll
        for (int ct = 0; ct < 5; ++ct) a0[ct] = A[((size_t)kb * 5 + ct) * 64 + lane];
        float f[8];
#pragma unroll
        for (int j = 0; j < 8; ++j) f[j] = xt[cur][q * 8 + j][wave * 16 + col];
        uint4 bq;
        bq.x = pk2(f[0], f[1]); bq.y = pk2(f[2], f[3]);
        bq.z = pk2(f[4], f[5]); bq.w = pk2(f[6], f[7]);
        short8 bf = __builtin_bit_cast(short8, bq);
#pragma unroll
        for (int ct = 0; ct < 5; ++ct) {
            short8 af = __builtin_bit_cast(short8, a0[ct]);
            acc[ct] = __builtin_amdgcn_mfma_f32_16x16x32_bf16(af, bf, acc[ct], 0, 0, 0);
        }
        // ---- xAfrag emit: row r2 (global (kb)*32+r2), dims dgroup*64 + dch*8..+7 ----
        {
            float g0[8];
#pragma unroll
            for (int j = 0; j < 8; ++j) g0[j] = xt[cur][r2][dch * 8 + j];
            uint4 v;
            v.x = pk2(g0[0], g0[1]); v.y = pk2(g0[2], g0[3]);
            v.z = pk2(g0[4], g0[5]); v.w = pk2(g0[6], g0[7]);
            size_t slot = (((size_t)kb * 2 + rh) * 32 + dgroup * 2 + kbh) * 64 + (t & 63);
            ((uint4*)xAfrag)[slot] = v;   // 1 KB contiguous per wave
        }
        if (havenext) {
            float* L = &xt[cur ^ 1][srow][sd];
            L[0] = u.x; L[1] = u.y; L[2] = u.z; L[3] = u.w;
            L[4] = v2.x; L[5] = v2.y; L[6] = v2.z; L[7] = v2.w;
        }
        __syncthreads();
    }
    float* pb = partial + (size_t)ks * CPAD * NDIM;
#pragma unroll
    for (int ct = 0; ct < 5; ++ct)
#pragma unroll
        for (int reg = 0; reg < 4; ++reg)
            pb[(size_t)(ct * 16 + q * 4 + reg) * NDIM + d] = acc[ct][reg];
}

// ---- kC: 80 blocks x 1024 thr; slice-reduce + counts + unit anchors + scale ----
__global__ __launch_bounds__(1024) void kC_fuse(const float* __restrict__ wptr,
                                                const unsigned* __restrict__ cntpart,
                                                const float* __restrict__ partial,
                                                int kslices,
                                                unsigned short* __restrict__ bfrag,
                                                float* __restrict__ scale,
                                                unsigned char* __restrict__ actB,
                                                unsigned* __restrict__ countsF,
                                                float* __restrict__ wsum,
                                                unsigned* __restrict__ done) {
    int c = blockIdx.x, t = threadIdx.x;
    __shared__ float red[16];
    __shared__ unsigned credu[4];
    __shared__ float bcast[1];
    if (c == 0 && t == 512) *wsum = 0.f;
    if (c == 0 && t == 513) *done = 0u;
    if (t < 256) {
        unsigned cv = cntpart[t * 80 + c];
#pragma unroll
        for (int m = 32; m >= 1; m >>= 1) cv += __shfl_xor(cv, m, 64);
        if ((t & 63) == 0) credu[t >> 6] = cv;
    }
    const float* p = partial + (size_t)c * NDIM + t;
    float s = 0.f;
#pragma unroll 8
    for (int sl = 0; sl < kslices; ++sl) s += p[(size_t)sl * CPAD * NDIM];
    float ss = s * s;
#pragma unroll
    for (int m = 32; m >= 1; m >>= 1) ss += __shfl_xor(ss, m, 64);
    if ((t & 63) == 0) red[t >> 6] = ss;
    __syncthreads();
    if (t == 0) {
        float tot = 0.f;
#pragma unroll
        for (int j = 0; j < 16; ++j) tot += red[j];
        bcast[0] = sqrtf(tot);
    }
    unsigned cnt = credu[0] + credu[1] + credu[2] + credu[3];
    __syncthreads();
    float invc = 1.0f / (float)(cnt > 0u ? cnt : 1u);
    float a = s * invc;
    float an = fmaxf(bcast[0] * invc, 1e-8f);
    unsigned short h = bf16u(a / an);
    int ct = c >> 4, colc = c & 15;
    int kb = t >> 5, q = (t >> 3) & 3, j0 = t & 7;
    bfrag[((((size_t)ct * 32 + kb) * 64) + q * 16 + colc) * 8 + j0] = h;
    float hv = __bfloat162float(__builtin_bit_cast(__hip_bfloat16, h));
    float nb2 = hv * hv;
#pragma unroll
    for (int m = 32; m >= 1; m >>= 1) nb2 += __shfl_xor(nb2, m, 64);
    if ((t & 63) == 0) red[t >> 6] = nb2;
    __syncthreads();
    if (t == 0) {
        float n2 = 0.f;
#pragma unroll
        for (int j = 0; j < 16; ++j) n2 += red[j];
        scale[c] = (n2 > 0.f) ? (wptr[0] / sqrtf(n2)) : 0.f;
        actB[c] = (cnt > 0u) ? 1 : 0;
        countsF[c] = cnt;
    }
}

// ---- k3: cos GEMM + fused loss; xn2 computed in-register from the bf16
// A-frags (denominator consistent with MFMA numerator); fence-free finalize ----
__global__ __launch_bounds__(256) void k3_loss(const unsigned short* __restrict__ xAfrag,
                                               const unsigned short* __restrict__ bfrag,
                                               const unsigned long long* __restrict__ masks,
                                               const unsigned char* __restrict__ actB,
                                               const float* __restrict__ scale,
                                               const float* __restrict__ bptr,
                                               float* __restrict__ wsum,
                                               unsigned* __restrict__ done,
                                               const unsigned* __restrict__ countsF,
                                               float* __restrict__ out) {
    __shared__ float redsm[3][64][21];   // stride 21: conflict-free
    __shared__ float sqred[4][16];       // per-wave row-norm2 partials (bf16-based)
    int t = threadIdx.x, wave = t >> 6, lane = t & 63;
    int q = lane >> 4, col = lane & 15;
    int rt = blockIdx.x;
    int rowbase = rt * 16;
    const uint4* A = (const uint4*)xAfrag + (size_t)rt * 32 * 64 + lane;
    const uint4* Bp = (const uint4*)bfrag + lane;
    int kb0 = wave * 8;

    float4v acc[5];
#pragma unroll
    for (int ct = 0; ct < 5; ++ct) acc[ct] = (float4v){0.f, 0.f, 0.f, 0.f};

    // batch all 8 A-frag loads (independent -> all in flight at once)
    uint4 a[8];
#pragma unroll
    for (int j = 0; j < 8; ++j) a[j] = A[(size_t)(kb0 + j) * 64];
    uint4 b0[5], b1[5];
#pragma unroll
    for (int ct = 0; ct < 5; ++ct) b0[ct] = Bp[(size_t)(ct * 32 + kb0 + 0) * 64];
#pragma unroll
    for (int ct = 0; ct < 5; ++ct) b1[ct] = Bp[(size_t)(ct * 32 + kb0 + 1) * 64];

    // row-norm^2 from bf16 fragments (useful VALU work while loads land)
    float sq = 0.f;
#pragma unroll
    for (int j = 0; j < 8; ++j) {
        const unsigned* dw = (const unsigned*)&a[j];
#pragma unroll
        for (int e = 0; e < 4; ++e) {
            float lo = __builtin_bit_cast(float, dw[e] << 16);
            float hi = __builtin_bit_cast(float, dw[e] & 0xffff0000u);
            sq = fmaf(lo, lo, sq);
            sq = fmaf(hi, hi, sq);
        }
    }
    sq += __shfl_xor(sq, 16, 64);
    sq += __shfl_xor(sq, 32, 64);
    if (lane < 16) sqred[wave][lane] = sq;

    for (int s = 0; s < 8; s += 2) {
        int p2 = s + 2 < 8 ? kb0 + s + 2 : kb0 + s;
        int p3 = s + 3 < 8 ? kb0 + s + 3 : kb0 + s + 1;
        {
            short8 af = __builtin_bit_cast(short8, a[s]);
#pragma unroll
            for (int ct = 0; ct < 5; ++ct) {
                short8 bf = __builtin_bit_cast(short8, b0[ct]);
                acc[ct] = __builtin_amdgcn_mfma_f32_16x16x32_bf16(af, bf, acc[ct], 0, 0, 0);
            }
#pragma unroll
            for (int ct = 0; ct < 5; ++ct) b0[ct] = Bp[(size_t)(ct * 32 + p2) * 64];
        }
        {
            short8 af = __builtin_bit_cast(short8, a[s + 1]);
#pragma unroll
            for (int ct = 0; ct < 5; ++ct) {
                short8 bf = __builtin_bit_cast(short8, b1[ct]);
                acc[ct] = __builtin_amdgcn_mfma_f32_16x16x32_bf16(af, bf, acc[ct], 0, 0, 0);
            }
#pragma unroll
            for (int ct = 0; ct < 5; ++ct) b1[ct] = Bp[(size_t)(ct * 32 + p3) * 64];
        }
    }

    if (wave) {
#pragma unroll
        for (int ct = 0; ct < 5; ++ct)
#pragma unroll
            for (int reg = 0; reg < 4; ++reg)
                redsm[wave - 1][lane][ct * 4 + reg] = acc[ct][reg];
    }
    __syncthreads();
    if (wave != 0) return;
#pragma unroll
    for (int w = 0; w < 3; ++w)
#pragma unroll
        for (int ct = 0; ct < 5; ++ct)
#pragma unroll
            for (int reg = 0; reg < 4; ++reg)
                acc[ct][reg] += redsm[w][lane][ct * 4 + reg];

    float bv = bptr[0];
    float sc[5]; unsigned char ab[5];
#pragma unroll
    for (int ct = 0; ct < 5; ++ct) { sc[ct] = scale[ct * 16 + col]; ab[ct] = actB[ct * 16 + col]; }

    float contrib = 0.f;
#pragma unroll
    for (int reg = 0; reg < 4; ++reg) {
        int rl = q * 4 + reg;
        int row = rowbase + rl;
        float xn2v = sqred[0][rl] + sqred[1][rl] + sqred[2][rl] + sqred[3][rl];
        float inv = 1.0f / fmaxf(sqrtf(xn2v), 1e-8f);
        unsigned long long mask = masks[row];
        float v[5]; float lmax = -1e30f;
#pragma unroll
        for (int ct = 0; ct < 5; ++ct) {
            float lg = acc[ct][reg] * sc[ct] * inv + bv;   // w*cos + b
            v[ct] = ab[ct] ? lg : -1e30f;
            lmax = fmaxf(lmax, v[ct]);
        }
#pragma unroll
        for (int m = 1; m < 16; m <<= 1) lmax = fmaxf(lmax, __shfl_xor(lmax, m, 16));
        float es = 0.f;
#pragma unroll
        for (int ct = 0; ct < 5; ++ct) es += __expf(v[ct] - lmax);
#pragma unroll
        for (int m = 1; m < 16; m <<= 1) es += __shfl_xor(es, m, 16);
        float lse = lmax + __logf(es);
        float ps = 0.f;
#pragma unroll
        for (int ct = 0; ct < 5; ++ct) {
            int c = ct * 16 + col;
            bool pos = (c < 64) ? (((mask >> c) & 1ull) != 0ull)
                                : ((c == 64) ? (mask == 0ull) : false);
            ps += pos ? v[ct] : 0.f;
        }
#pragma unroll
        for (int m = 1; m < 16; m <<= 1) ps += __shfl_xor(ps, m, 16);
        float npos = mask ? (float)__popcll(mask) : 1.0f;
        float crow = ps - npos * lse;
        if (col == 0) contrib += crow;
    }
#pragma unroll
    for (int m = 1; m < 64; m <<= 1) contrib += __shfl_xor(contrib, m, 64);
    if (lane == 0) {
        atomicAdd(wsum, contrib);
        asm volatile("s_waitcnt vmcnt(0)" ::: "memory");
        unsigned prev = atomicAdd(done, 1u);
        if (prev == (unsigned)gridDim.x - 1u) {
            float wv = __hip_atomic_load(wsum, __ATOMIC_ACQUIRE, __HIP_MEMORY_SCOPE_AGENT);
            float np = 0.f;
            for (int c = 0; c < NC; ++c) np += (float)countsF[c];
            out[0] = -wv / np;
        }
    }
}

extern "C" void kernel_launch(void* const* d_in, const int* in_sizes, int n_in,
                              void* d_out, int out_size, void* d_ws, size_t ws_size,
                              hipStream_t stream) {
    (void)in_sizes; (void)n_in; (void)out_size;
    const float* x = (const float*)d_in[0];
    const int* label = (const int*)d_in[1];
    const float* w = (const float*)d_in[2];
    const float* b = (const float*)d_in[3];

    char* ws = (char*)d_ws;
    float* scale = (float*)(ws + SCALE_B);
    unsigned char* actB = (unsigned char*)(ws + ACTB_B);
    float* wsum = (float*)(ws + WSUM_B);
    unsigned* done = (unsigned*)(ws + DONE_B);
    unsigned* countsF = (unsigned*)(ws + CNTF_B);
    unsigned* cntpart = (unsigned*)(ws + CNTP_B);
    unsigned long long* masks = (unsigned long long*)(ws + MASK_B);
    unsigned short* lfrag = (unsigned short*)(ws + LFRAG_B);
    unsigned short* bfrag = (unsigned short*)(ws + BFRAG_B);
    unsigned short* xAfrag = (unsigned short*)(ws + XAF_B);
    float* partial = (float*)(ws + PART_B);

    int kslices = 64;
    while (kslices > 8 && PART_B + (size_t)kslices * SLAB > ws_size) kslices >>= 1;

    hipLaunchKernelGGL(kA_labels, dim3(256), dim3(256), 0, stream,
                       label, masks, cntpart, lfrag);
    hipLaunchKernelGGL(kG, dim3(16 * kslices), dim3(256), 0, stream,
                       x, lfrag, partial, xAfrag, kslices);
    hipLaunchKernelGGL(kC_fuse, dim3(CPAD), dim3(1024), 0, stream,
                       w, cntpart, partial, kslices, bfrag, scale, actB, countsF, wsum, done);
    hipLaunchKernelGGL(k3_loss, dim3(NROWS / 16), dim3(256), 0, stream,
                       xAfrag, bfrag, masks, actB, scale, b, wsum, done, countsF, (float*)d_out);
}

// Round 9
// 147.728 us; speedup vs baseline: 1.2378x; 1.2378x over previous
//
#include <hip/hip_runtime.h>
#include <hip/hip_bf16.h>
#include <stdint.h>

#define NROWS 16384
#define NDIM  1024
#define NLAB  64
#define NC    65
#define CPAD  80

typedef float float4v __attribute__((ext_vector_type(4)));
typedef short short8  __attribute__((ext_vector_type(8)));

// ---- workspace layout (bytes); nothing needs pre-zeroing ----
static constexpr size_t SCALE_B = 0;         // 80 f32
static constexpr size_t ACTB_B  = 320;       // 80 u8
static constexpr size_t CNTF_B  = 448;       // 80 u32 counts
static constexpr size_t CNTP_B  = 1024;      // 256 x 80 u32 count slabs
static constexpr size_t MASK_B  = 83968;     // 16384 u64 row masks
static constexpr size_t XN2_B   = 215040;    // 16384 f32 row norms^2
static constexpr size_t LFRAG_B = 280576;    // labT bf16 A-frag (2.6 MB)
static constexpr size_t BFRAG_B = 2902016;   // unit anchors bf16 B-frag (160 KB)
static constexpr size_t XAF_B   = 3065856;   // x bf16 A-frag (32 MB)
static constexpr size_t PART_B  = 36620288;  // kslices*80*1024 f32 partials
static constexpr size_t SLAB    = (size_t)CPAD * NDIM * 4;
static constexpr size_t WARR_B  = 60000256;  // 1024 f32 per-block loss partials

__device__ __forceinline__ unsigned short bf16u(float f) {
    __hip_bfloat16 h = __float2bfloat16(f);
    return __builtin_bit_cast(unsigned short, h);
}
__device__ __forceinline__ unsigned pk2(float a, float b) {
    return (unsigned)bf16u(a) | ((unsigned)bf16u(b) << 16);
}

// ---- kA: labels only; 256 blocks -> masks, cntpart, lfrag (verified) ----
__global__ __launch_bounds__(256) void kA_labels(const int* __restrict__ label,
                                                 unsigned long long* __restrict__ masks,
                                                 unsigned* __restrict__ cntpart,
                                                 unsigned short* __restrict__ lfrag) {
    __shared__ unsigned cnt[NC];
    __shared__ unsigned long long smask[64];
    int t = threadIdx.x;
    int bid = blockIdx.x;
    if (t < NC) cnt[t] = 0;
    __syncthreads();
    int wave = t >> 6, lane = t & 63;
    int rowblock = bid * 64;
    unsigned creg = 0, zreg = 0;
#pragma unroll 4
    for (int p = 0; p < 16; ++p) {
        int row = rowblock + p * 4 + wave;
        int v = label[row * NLAB + lane];
        unsigned long long m = __ballot(v != 0);
        creg += (unsigned)((m >> lane) & 1ull);
        if (lane == 0) {
            masks[row] = m;
            smask[p * 4 + wave] = m;
            zreg += (m == 0ull) ? 1u : 0u;
        }
    }
    atomicAdd(&cnt[lane], creg);
    if (lane == 0 && zreg) atomicAdd(&cnt[64], zreg);
    __syncthreads();
    if (t < 80) cntpart[bid * 80 + t] = (t < NC) ? cnt[t] : 0u;
    for (int pid = t; pid < 640; pid += 256) {
        int rt2l = pid / 320, rem = pid % 320;
        int ct = rem >> 6, ln = rem & 63;
        int qq = ln >> 4, cc = ln & 15;
        int c = ct * 16 + cc;
        int rbase = rt2l * 32 + qq * 8;
        unsigned pk[4];
#pragma unroll
        for (int jp = 0; jp < 4; ++jp) {
            unsigned long long m0 = smask[rbase + jp * 2], m1 = smask[rbase + jp * 2 + 1];
            unsigned b0, b1;
            if (c < 64)       { b0 = (unsigned)((m0 >> c) & 1ull); b1 = (unsigned)((m1 >> c) & 1ull); }
            else if (c == 64) { b0 = (m0 == 0ull); b1 = (m1 == 0ull); }
            else              { b0 = 0u; b1 = 0u; }
            pk[jp] = (b0 ? 0x3F80u : 0u) | (b1 ? 0x3F800000u : 0u);
        }
        uint4 w = make_uint4(pk[0], pk[1], pk[2], pk[3]);
        ((uint4*)lfrag)[((size_t)(bid * 2 + rt2l) * 5 + ct) * 64 + ln] = w;
    }
}

// ---- kBP: blocks 0..16*kslices-1 = anchor GEMM (LDS-staged, verified);
//           blocks 16*kslices..+1023 = x prep in-register (verified). ----
__global__ __launch_bounds__(256) void kBP(const float* __restrict__ x,
                                           const unsigned short* __restrict__ lfrag,
                                           float* __restrict__ partial,
                                           unsigned short* __restrict__ xAfrag,
                                           float* __restrict__ xn2g,
                                           int kslices) {
    __shared__ float xt[2][32][65];
    __shared__ float red2[4][16];
    int t = threadIdx.x, wave = t >> 6, lane = t & 63;
    int q = lane >> 4, col = lane & 15;
    int ngemm = 16 * kslices;

    if ((int)blockIdx.x >= ngemm) {
        int rt = blockIdx.x - ngemm;
        const float* rowp = x + ((size_t)rt * 16 + col) * NDIM;
        uint4* dst = (uint4*)xAfrag + ((size_t)rt * 32 + wave * 8) * 64 + lane;
        float4 fa[8], fb[8];
#pragma unroll
        for (int kb = 0; kb < 8; ++kb) {
            int d0 = wave * 256 + kb * 32 + q * 8;
            fa[kb] = *(const float4*)(rowp + d0);
            fb[kb] = *(const float4*)(rowp + d0 + 4);
        }
        float sq = 0.f;
#pragma unroll
        for (int kb = 0; kb < 8; ++kb) {
            sq += fa[kb].x * fa[kb].x + fa[kb].y * fa[kb].y + fa[kb].z * fa[kb].z + fa[kb].w * fa[kb].w
                + fb[kb].x * fb[kb].x + fb[kb].y * fb[kb].y + fb[kb].z * fb[kb].z + fb[kb].w * fb[kb].w;
            uint4 v;
            v.x = pk2(fa[kb].x, fa[kb].y); v.y = pk2(fa[kb].z, fa[kb].w);
            v.z = pk2(fb[kb].x, fb[kb].y); v.w = pk2(fb[kb].z, fb[kb].w);
            dst[kb * 64] = v;
        }
        sq += __shfl_xor(sq, 16, 64);
        sq += __shfl_xor(sq, 32, 64);
        if (q == 0) red2[wave][col] = sq;
        __syncthreads();
        if (t < 16) xn2g[rt * 16 + t] = red2[0][t] + red2[1][t] + red2[2][t] + red2[3][t];
        return;
    }

    int dgroup = blockIdx.x & 15, ks = blockIdx.x >> 4;
    int nkb = (NROWS / kslices) >> 5;
    int kb0 = ks * nkb;
    int d = dgroup * 64 + wave * 16 + col;
    const uint4* A = (const uint4*)lfrag;
    int srow = t >> 3, sd = (t & 7) * 8;

    float4v acc[5];
#pragma unroll
    for (int ct = 0; ct < 5; ++ct) acc[ct] = (float4v){0.f, 0.f, 0.f, 0.f};

    {
        const float* g = x + ((size_t)(kb0 * 32 + srow)) * NDIM + dgroup * 64 + sd;
        float4 u = *(const float4*)g, v2 = *(const float4*)(g + 4);
        float* L = &xt[0][srow][sd];
        L[0] = u.x; L[1] = u.y; L[2] = u.z; L[3] = u.w;
        L[4] = v2.x; L[5] = v2.y; L[6] = v2.z; L[7] = v2.w;
    }
    __syncthreads();

    for (int i = 0; i < nkb; ++i) {
        int cur = i & 1;
        float4 u, v2;
        bool havenext = (i + 1) < nkb;
        if (havenext) {
            const float* g = x + ((size_t)((kb0 + i + 1) * 32 + srow)) * NDIM + dgroup * 64 + sd;
            u = *(const float4*)g; v2 = *(const float4*)(g + 4);
        }
        int kb = kb0 + i;
        uint4 a0[5];
#pragma unroll
        for (int ct = 0; ct < 5; ++ct) a0[ct] = A[((size_t)kb * 5 + ct) * 64 + lane];
        float f[8];
#pragma unroll
        for (int j = 0; j < 8; ++j) f[j] = xt[cur][q * 8 + j][wave * 16 + col];
        uint4 bq;
        bq.x = pk2(f[0], f[1]); bq.y = pk2(f[2], f[3]);
        bq.z = pk2(f[4], f[5]); bq.w = pk2(f[6], f[7]);
        short8 bf = __builtin_bit_cast(short8, bq);
#pragma unroll
        for (int ct = 0; ct < 5; ++ct) {
            short8 af = __builtin_bit_cast(short8, a0[ct]);
            acc[ct] = __builtin_amdgcn_mfma_f32_16x16x32_bf16(af, bf, acc[ct], 0, 0, 0);
        }
        if (havenext) {
            float* L = &xt[cur ^ 1][srow][sd];
            L[0] = u.x; L[1] = u.y; L[2] = u.z; L[3] = u.w;
            L[4] = v2.x; L[5] = v2.y; L[6] = v2.z; L[7] = v2.w;
        }
        __syncthreads();
    }
    float* pb = partial + (size_t)ks * CPAD * NDIM;
#pragma unroll
    for (int ct = 0; ct < 5; ++ct)
#pragma unroll
        for (int reg = 0; reg < 4; ++reg)
            pb[(size_t)(ct * 16 + q * 4 + reg) * NDIM + d] = acc[ct][reg];
}

// ---- kC: 80 blocks x 1024 thr; slice-reduce + counts + unit anchors + scale ----
__global__ __launch_bounds__(1024) void kC_fuse(const float* __restrict__ wptr,
                                                const unsigned* __restrict__ cntpart,
                                                const float* __restrict__ partial,
                                                int kslices,
                                                unsigned short* __restrict__ bfrag,
                                                float* __restrict__ scale,
                                                unsigned char* __restrict__ actB,
                                                unsigned* __restrict__ countsF) {
    int c = blockIdx.x, t = threadIdx.x;
    __shared__ float red[16];
    __shared__ unsigned credu[4];
    __shared__ float bcast[1];
    if (t < 256) {
        unsigned cv = cntpart[t * 80 + c];
#pragma unroll
        for (int m = 32; m >= 1; m >>= 1) cv += __shfl_xor(cv, m, 64);
        if ((t & 63) == 0) credu[t >> 6] = cv;
    }
    const float* p = partial + (size_t)c * NDIM + t;
    float s = 0.f;
#pragma unroll 8
    for (int sl = 0; sl < kslices; ++sl) s += p[(size_t)sl * CPAD * NDIM];
    float ss = s * s;
#pragma unroll
    for (int m = 32; m >= 1; m >>= 1) ss += __shfl_xor(ss, m, 64);
    if ((t & 63) == 0) red[t >> 6] = ss;
    __syncthreads();
    if (t == 0) {
        float tot = 0.f;
#pragma unroll
        for (int j = 0; j < 16; ++j) tot += red[j];
        bcast[0] = sqrtf(tot);
    }
    unsigned cnt = credu[0] + credu[1] + credu[2] + credu[3];
    __syncthreads();
    float invc = 1.0f / (float)(cnt > 0u ? cnt : 1u);
    float a = s * invc;
    float an = fmaxf(bcast[0] * invc, 1e-8f);
    unsigned short h = bf16u(a / an);
    int ct = c >> 4, colc = c & 15;
    int kb = t >> 5, q = (t >> 3) & 3, j0 = t & 7;
    bfrag[((((size_t)ct * 32 + kb) * 64) + q * 16 + colc) * 8 + j0] = h;
    float hv = __bfloat162float(__builtin_bit_cast(__hip_bfloat16, h));
    float nb2 = hv * hv;
#pragma unroll
    for (int m = 32; m >= 1; m >>= 1) nb2 += __shfl_xor(nb2, m, 64);
    if ((t & 63) == 0) red[t >> 6] = nb2;
    __syncthreads();
    if (t == 0) {
        float n2 = 0.f;
#pragma unroll
        for (int j = 0; j < 16; ++j) n2 += red[j];
        scale[c] = (n2 > 0.f) ? (wptr[0] / sqrtf(n2)) : 0.f;
        actB[c] = (cnt > 0u) ? 1 : 0;
        countsF[c] = cnt;
    }
}

// ---- k3: cos GEMM + fused loss; NO atomics — per-block store to wsumArr ----
__global__ __launch_bounds__(256) void k3_loss(const unsigned short* __restrict__ xAfrag,
                                               const unsigned short* __restrict__ bfrag,
                                               const float* __restrict__ xn2g,
                                               const unsigned long long* __restrict__ masks,
                                               const unsigned char* __restrict__ actB,
                                               const float* __restrict__ scale,
                                               const float* __restrict__ bptr,
                                               float* __restrict__ wsumArr) {
    __shared__ float redsm[3][64][21];   // stride 21: conflict-free
    int t = threadIdx.x, wave = t >> 6, lane = t & 63;
    int q = lane >> 4, col = lane & 15;
    int rt = blockIdx.x;
    int rowbase = rt * 16;
    const uint4* A = (const uint4*)xAfrag + (size_t)rt * 32 * 64 + lane;
    const uint4* Bp = (const uint4*)bfrag + lane;
    int kb0 = wave * 8;

    float4v acc[5];
#pragma unroll
    for (int ct = 0; ct < 5; ++ct) acc[ct] = (float4v){0.f, 0.f, 0.f, 0.f};

    uint4 a[8];
#pragma unroll
    for (int j = 0; j < 8; ++j) a[j] = A[(size_t)(kb0 + j) * 64];
    uint4 b0[5], b1[5];
#pragma unroll
    for (int ct = 0; ct < 5; ++ct) b0[ct] = Bp[(size_t)(ct * 32 + kb0 + 0) * 64];
#pragma unroll
    for (int ct = 0; ct < 5; ++ct) b1[ct] = Bp[(size_t)(ct * 32 + kb0 + 1) * 64];

    for (int s = 0; s < 8; s += 2) {
        int p2 = s + 2 < 8 ? kb0 + s + 2 : kb0 + s;
        int p3 = s + 3 < 8 ? kb0 + s + 3 : kb0 + s + 1;
        {
            short8 af = __builtin_bit_cast(short8, a[s]);
#pragma unroll
            for (int ct = 0; ct < 5; ++ct) {
                short8 bf = __builtin_bit_cast(short8, b0[ct]);
                acc[ct] = __builtin_amdgcn_mfma_f32_16x16x32_bf16(af, bf, acc[ct], 0, 0, 0);
            }
#pragma unroll
            for (int ct = 0; ct < 5; ++ct) b0[ct] = Bp[(size_t)(ct * 32 + p2) * 64];
        }
        {
            short8 af = __builtin_bit_cast(short8, a[s + 1]);
#pragma unroll
            for (int ct = 0; ct < 5; ++ct) {
                short8 bf = __builtin_bit_cast(short8, b1[ct]);
                acc[ct] = __builtin_amdgcn_mfma_f32_16x16x32_bf16(af, bf, acc[ct], 0, 0, 0);
            }
#pragma unroll
            for (int ct = 0; ct < 5; ++ct) b1[ct] = Bp[(size_t)(ct * 32 + p3) * 64];
        }
    }

    if (wave) {
#pragma unroll
        for (int ct = 0; ct < 5; ++ct)
#pragma unroll
            for (int reg = 0; reg < 4; ++reg)
                redsm[wave - 1][lane][ct * 4 + reg] = acc[ct][reg];
    }
    __syncthreads();
    if (wave != 0) return;
#pragma unroll
    for (int w = 0; w < 3; ++w)
#pragma unroll
        for (int ct = 0; ct < 5; ++ct)
#pragma unroll
            for (int reg = 0; reg < 4; ++reg)
                acc[ct][reg] += redsm[w][lane][ct * 4 + reg];

    float bv = bptr[0];
    float sc[5]; unsigned char ab[5];
#pragma unroll
    for (int ct = 0; ct < 5; ++ct) { sc[ct] = scale[ct * 16 + col]; ab[ct] = actB[ct * 16 + col]; }

    float contrib = 0.f;
#pragma unroll
    for (int reg = 0; reg < 4; ++reg) {
        int rl = q * 4 + reg;
        int row = rowbase + rl;
        float inv = 1.0f / fmaxf(sqrtf(xn2g[row]), 1e-8f);
        unsigned long long mask = masks[row];
        float v[5]; float lmax = -1e30f;
#pragma unroll
        for (int ct = 0; ct < 5; ++ct) {
            float lg = acc[ct][reg] * sc[ct] * inv + bv;   // w*cos + b
            v[ct] = ab[ct] ? lg : -1e30f;
            lmax = fmaxf(lmax, v[ct]);
        }
#pragma unroll
        for (int m = 1; m < 16; m <<= 1) lmax = fmaxf(lmax, __shfl_xor(lmax, m, 16));
        float es = 0.f;
#pragma unroll
        for (int ct = 0; ct < 5; ++ct) es += __expf(v[ct] - lmax);
#pragma unroll
        for (int m = 1; m < 16; m <<= 1) es += __shfl_xor(es, m, 16);
        float lse = lmax + __logf(es);
        float ps = 0.f;
#pragma unroll
        for (int ct = 0; ct < 5; ++ct) {
            int c = ct * 16 + col;
            bool pos = (c < 64) ? (((mask >> c) & 1ull) != 0ull)
                                : ((c == 64) ? (mask == 0ull) : false);
            ps += pos ? v[ct] : 0.f;
        }
#pragma unroll
        for (int m = 1; m < 16; m <<= 1) ps += __shfl_xor(ps, m, 16);
        float npos = mask ? (float)__popcll(mask) : 1.0f;
        float crow = ps - npos * lse;
        if (col == 0) contrib += crow;
    }
#pragma unroll
    for (int m = 1; m < 64; m <<= 1) contrib += __shfl_xor(contrib, m, 64);
    if (lane == 0) wsumArr[rt] = contrib;    // plain coalesced store; no atomic
}

// ---- kE: reduce 1024 block partials + n_pairs -> loss ----
__global__ __launch_bounds__(256) void kE_final(const float* __restrict__ wsumArr,
                                                const unsigned* __restrict__ countsF,
                                                float* __restrict__ out) {
    __shared__ float red[4];
    int t = threadIdx.x, wave = t >> 6, lane = t & 63;
    float s = wsumArr[t] + wsumArr[t + 256] + wsumArr[t + 512] + wsumArr[t + 768];
#pragma unroll
    for (int m = 32; m >= 1; m >>= 1) s += __shfl_xor(s, m, 64);
    if (lane == 0) red[wave] = s;
    __syncthreads();
    if (t == 0) {
        float wv = red[0] + red[1] + red[2] + red[3];
        float np = 0.f;
        for (int c = 0; c < NC; ++c) np += (float)countsF[c];
        out[0] = -wv / np;
    }
}

extern "C" void kernel_launch(void* const* d_in, const int* in_sizes, int n_in,
                              void* d_out, int out_size, void* d_ws, size_t ws_size,
                              hipStream_t stream) {
    (void)in_sizes; (void)n_in; (void)out_size;
    const float* x = (const float*)d_in[0];
    const int* label = (const int*)d_in[1];
    const float* w = (const float*)d_in[2];
    const float* b = (const float*)d_in[3];

    char* ws = (char*)d_ws;
    float* scale = (float*)(ws + SCALE_B);
    unsigned char* actB = (unsigned char*)(ws + ACTB_B);
    unsigned* countsF = (unsigned*)(ws + CNTF_B);
    unsigned* cntpart = (unsigned*)(ws + CNTP_B);
    unsigned long long* masks = (unsigned long long*)(ws + MASK_B);
    float* xn2g = (float*)(ws + XN2_B);
    unsigned short* lfrag = (unsigned short*)(ws + LFRAG_B);
    unsigned short* bfrag = (unsigned short*)(ws + BFRAG_B);
    unsigned short* xAfrag = (unsigned short*)(ws + XAF_B);
    float* partial = (float*)(ws + PART_B);
    float* wsumArr = (float*)(ws + WARR_B);

    int kslices = 64;
    while (kslices > 8 && PART_B + (size_t)kslices * SLAB > WARR_B) kslices >>= 1;
    (void)ws_size;

    hipLaunchKernelGGL(kA_labels, dim3(256), dim3(256), 0, stream,
                       label, masks, cntpart, lfrag);
    hipLaunchKernelGGL(kBP, dim3(16 * kslices + 1024), dim3(256), 0, stream,
                       x, lfrag, partial, xAfrag, xn2g, kslices);
    hipLaunchKernelGGL(kC_fuse, dim3(CPAD), dim3(1024), 0, stream,
                       w, cntpart, partial, kslices, bfrag, scale, actB, countsF);
    hipLaunchKernelGGL(k3_loss, dim3(NROWS / 16), dim3(256), 0, stream,
                       xAfrag, bfrag, xn2g, masks, actB, scale, b, wsumArr);
    hipLaunchKernelGGL(kE_final, dim3(1), dim3(256), 0, stream,
                       wsumArr, countsF, (float*)d_out);
}

// Round 10
// 146.876 us; speedup vs baseline: 1.2449x; 1.0058x over previous
//
#include <hip/hip_runtime.h>
#include <hip/hip_bf16.h>
#include <stdint.h>

#define NROWS 16384
#define NDIM  1024
#define NLAB  64
#define NC    65
#define CPAD  80

typedef float float4v __attribute__((ext_vector_type(4)));
typedef short short8  __attribute__((ext_vector_type(8)));

// ---- workspace layout (bytes); nothing needs pre-zeroing ----
static constexpr size_t SCALE_B = 0;         // 80 f32
static constexpr size_t ACTB_B  = 320;       // 80 u8
static constexpr size_t CNTF_B  = 448;       // 80 u32 counts
static constexpr size_t CNTP_B  = 1024;      // 256 x 80 u32 count slabs
static constexpr size_t MASK_B  = 83968;     // 16384 u64 row masks
static constexpr size_t XN2_B   = 215040;    // 16384 f32 row norms^2
static constexpr size_t LFRAG_B = 280576;    // labT bf16 A-frag (2.6 MB)
static constexpr size_t BFRAG_B = 2902016;   // unit anchors bf16 B-frag (160 KB)
static constexpr size_t XAF_B   = 3065856;   // x bf16 A-frag (32 MB)
static constexpr size_t PART_B  = 36620288;  // kslices*80*1024 f32 partials
static constexpr size_t SLAB    = (size_t)CPAD * NDIM * 4;
static constexpr size_t WARR_B  = 60000256;  // 1024 f32 per-block loss partials
static constexpr size_t XN2P_B  = 61000192;  // 16 x 16384 f32 xn2 partials (1 MB)

__device__ __forceinline__ unsigned short bf16u(float f) {
    __hip_bfloat16 h = __float2bfloat16(f);
    return __builtin_bit_cast(unsigned short, h);
}
__device__ __forceinline__ unsigned pk2(float a, float b) {
    return (unsigned)bf16u(a) | ((unsigned)bf16u(b) << 16);
}

// ---- kA: labels only; 256 blocks -> masks, cntpart, lfrag (verified) ----
__global__ __launch_bounds__(256) void kA_labels(const int* __restrict__ label,
                                                 unsigned long long* __restrict__ masks,
                                                 unsigned* __restrict__ cntpart,
                                                 unsigned short* __restrict__ lfrag) {
    __shared__ unsigned cnt[NC];
    __shared__ unsigned long long smask[64];
    int t = threadIdx.x;
    int bid = blockIdx.x;
    if (t < NC) cnt[t] = 0;
    __syncthreads();
    int wave = t >> 6, lane = t & 63;
    int rowblock = bid * 64;
    unsigned creg = 0, zreg = 0;
#pragma unroll 4
    for (int p = 0; p < 16; ++p) {
        int row = rowblock + p * 4 + wave;
        int v = label[row * NLAB + lane];
        unsigned long long m = __ballot(v != 0);
        creg += (unsigned)((m >> lane) & 1ull);
        if (lane == 0) {
            masks[row] = m;
            smask[p * 4 + wave] = m;
            zreg += (m == 0ull) ? 1u : 0u;
        }
    }
    atomicAdd(&cnt[lane], creg);
    if (lane == 0 && zreg) atomicAdd(&cnt[64], zreg);
    __syncthreads();
    if (t < 80) cntpart[bid * 80 + t] = (t < NC) ? cnt[t] : 0u;
    for (int pid = t; pid < 640; pid += 256) {
        int rt2l = pid / 320, rem = pid % 320;
        int ct = rem >> 6, ln = rem & 63;
        int qq = ln >> 4, cc = ln & 15;
        int c = ct * 16 + cc;
        int rbase = rt2l * 32 + qq * 8;
        unsigned pk[4];
#pragma unroll
        for (int jp = 0; jp < 4; ++jp) {
            unsigned long long m0 = smask[rbase + jp * 2], m1 = smask[rbase + jp * 2 + 1];
            unsigned b0, b1;
            if (c < 64)       { b0 = (unsigned)((m0 >> c) & 1ull); b1 = (unsigned)((m1 >> c) & 1ull); }
            else if (c == 64) { b0 = (m0 == 0ull); b1 = (m1 == 0ull); }
            else              { b0 = 0u; b1 = 0u; }
            pk[jp] = (b0 ? 0x3F80u : 0u) | (b1 ? 0x3F800000u : 0u);
        }
        uint4 w = make_uint4(pk[0], pk[1], pk[2], pk[3]);
        ((uint4*)lfrag)[((size_t)(bid * 2 + rt2l) * 5 + ct) * 64 + ln] = w;
    }
}

// ---- kG: anchor GEMM (labT @ x) + xAfrag emit + xn2 partials, all from the
// SAME LDS-staged f32 tile. x is read from HBM exactly once.
// grid = 16 * kslices (kslices=64 -> 1024 blocks) ----
__global__ __launch_bounds__(256) void kG(const float* __restrict__ x,
                                          const unsigned short* __restrict__ lfrag,
                                          float* __restrict__ partial,
                                          unsigned short* __restrict__ xAfrag,
                                          float* __restrict__ xn2p,
                                          int kslices) {
    __shared__ float xt[2][32][65];
    __shared__ float sqacc[2][32][8];
    int t = threadIdx.x, wave = t >> 6, lane = t & 63;
    int q = lane >> 4, col = lane & 15;
    int dgroup = blockIdx.x & 15, ks = blockIdx.x >> 4;
    int nkb = (NROWS / kslices) >> 5;
    int kb0 = ks * nkb;
    int d = dgroup * 64 + wave * 16 + col;
    const uint4* A = (const uint4*)lfrag;
    int srow = t >> 3, sd = (t & 7) * 8;

    // emit-pass thread mapping
    int rh = t >> 7;              // row half of the 32-row tile
    int kbh = (t >> 6) & 1;       // 32-dim half of the 64-dim slice
    int qq = (t >> 4) & 3;
    int cc = t & 15;
    int r2 = rh * 16 + cc;        // LDS row
    int dch = kbh * 4 + qq;       // 8-dim chunk within the 64-dim slice

    float4v acc[5];
#pragma unroll
    for (int ct = 0; ct < 5; ++ct) acc[ct] = (float4v){0.f, 0.f, 0.f, 0.f};

    {
        const float* g = x + ((size_t)(kb0 * 32 + srow)) * NDIM + dgroup * 64 + sd;
        float4 u = *(const float4*)g, v2 = *(const float4*)(g + 4);
        float* L = &xt[0][srow][sd];
        L[0] = u.x; L[1] = u.y; L[2] = u.z; L[3] = u.w;
        L[4] = v2.x; L[5] = v2.y; L[6] = v2.z; L[7] = v2.w;
    }
    __syncthreads();

    for (int i = 0; i < nkb; ++i) {
        int cur = i & 1;
        // harvest previous iteration's xn2 partials (post-barrier safe)
        if (i > 0 && t < 32) {
            float s8 = 0.f;
#pragma unroll
            for (int d2 = 0; d2 < 8; ++d2) s8 += sqacc[(i - 1) & 1][t][d2];
            xn2p[(size_t)dgroup * NROWS + (size_t)(kb0 + i - 1) * 32 + t] = s8;
        }
        float4 u, v2;
        bool havenext = (i + 1) < nkb;
        if (havenext) {
            const float* g = x + ((size_t)((kb0 + i + 1) * 32 + srow)) * NDIM + dgroup * 64 + sd;
            u = *(const float4*)g; v2 = *(const float4*)(g + 4);
        }
        int kb = kb0 + i;
        uint4 a0[5];
#pragma unroll
        for (int ct = 0; ct < 5; ++ct) a0[ct] = A[((size_t)kb * 5 + ct) * 64 + lane];
        float f[8];
#pragma unroll
        for (int j = 0; j < 8; ++j) f[j] = xt[cur][q * 8 + j][wave * 16 + col];
        uint4 bq;
        bq.x = pk2(f[0], f[1]); bq.y = pk2(f[2], f[3]);
        bq.z = pk2(f[4], f[5]); bq.w = pk2(f[6], f[7]);
        short8 bf = __builtin_bit_cast(short8, bq);
#pragma unroll
        for (int ct = 0; ct < 5; ++ct) {
            short8 af = __builtin_bit_cast(short8, a0[ct]);
            acc[ct] = __builtin_amdgcn_mfma_f32_16x16x32_bf16(af, bf, acc[ct], 0, 0, 0);
        }
        // xAfrag emit + xn2 partial from the same LDS tile
        {
            float g0[8];
#pragma unroll
            for (int j = 0; j < 8; ++j) g0[j] = xt[cur][r2][dch * 8 + j];
            float sp = 0.f;
#pragma unroll
            for (int j = 0; j < 8; ++j) sp += g0[j] * g0[j];
            sqacc[cur][r2][dch] = sp;
            uint4 v;
            v.x = pk2(g0[0], g0[1]); v.y = pk2(g0[2], g0[3]);
            v.z = pk2(g0[4], g0[5]); v.w = pk2(g0[6], g0[7]);
            size_t slot = (((size_t)kb * 2 + rh) * 32 + dgroup * 2 + kbh) * 64 + (t & 63);
            ((uint4*)xAfrag)[slot] = v;
        }
        if (havenext) {
            float* L = &xt[cur ^ 1][srow][sd];
            L[0] = u.x; L[1] = u.y; L[2] = u.z; L[3] = u.w;
            L[4] = v2.x; L[5] = v2.y; L[6] = v2.z; L[7] = v2.w;
        }
        __syncthreads();
    }
    // final harvest
    if (t < 32) {
        float s8 = 0.f;
#pragma unroll
        for (int d2 = 0; d2 < 8; ++d2) s8 += sqacc[(nkb - 1) & 1][t][d2];
        xn2p[(size_t)dgroup * NROWS + (size_t)(kb0 + nkb - 1) * 32 + t] = s8;
    }
    float* pb = partial + (size_t)ks * CPAD * NDIM;
#pragma unroll
    for (int ct = 0; ct < 5; ++ct)
#pragma unroll
        for (int reg = 0; reg < 4; ++reg)
            pb[(size_t)(ct * 16 + q * 4 + reg) * NDIM + d] = acc[ct][reg];
}

// ---- kC: 80 blocks x 1024 thr; slice-reduce + counts + unit anchors + scale
// + xn2 partial reduce (idle-thread work) ----
__global__ __launch_bounds__(1024) void kC_fuse(const float* __restrict__ wptr,
                                                const unsigned* __restrict__ cntpart,
                                                const float* __restrict__ partial,
                                                int kslices,
                                                unsigned short* __restrict__ bfrag,
                                                float* __restrict__ scale,
                                                unsigned char* __restrict__ actB,
                                                unsigned* __restrict__ countsF,
                                                const float* __restrict__ xn2p,
                                                float* __restrict__ xn2g) {
    int c = blockIdx.x, t = threadIdx.x;
    __shared__ float red[16];
    __shared__ unsigned credu[4];
    __shared__ float bcast[1];
    if (t < 256) {
        unsigned cv = cntpart[t * 80 + c];
#pragma unroll
        for (int m = 32; m >= 1; m >>= 1) cv += __shfl_xor(cv, m, 64);
        if ((t & 63) == 0) credu[t >> 6] = cv;
    }
    // xn2 partial reduce: blocks 0..15 cover all 16384 rows
    int gid = c * 1024 + t;
    if (gid < NROWS) {
        float s2 = 0.f;
#pragma unroll
        for (int dg = 0; dg < 16; ++dg) s2 += xn2p[(size_t)dg * NROWS + gid];
        xn2g[gid] = s2;
    }
    const float* p = partial + (size_t)c * NDIM + t;
    float s = 0.f;
#pragma unroll 8
    for (int sl = 0; sl < kslices; ++sl) s += p[(size_t)sl * CPAD * NDIM];
    float ss = s * s;
#pragma unroll
    for (int m = 32; m >= 1; m >>= 1) ss += __shfl_xor(ss, m, 64);
    if ((t & 63) == 0) red[t >> 6] = ss;
    __syncthreads();
    if (t == 0) {
        float tot = 0.f;
#pragma unroll
        for (int j = 0; j < 16; ++j) tot += red[j];
        bcast[0] = sqrtf(tot);
    }
    unsigned cnt = credu[0] + credu[1] + credu[2] + credu[3];
    __syncthreads();
    float invc = 1.0f / (float)(cnt > 0u ? cnt : 1u);
    float a = s * invc;
    float an = fmaxf(bcast[0] * invc, 1e-8f);
    unsigned short h = bf16u(a / an);
    int ct = c >> 4, colc = c & 15;
    int kb = t >> 5, q = (t >> 3) & 3, j0 = t & 7;
    bfrag[((((size_t)ct * 32 + kb) * 64) + q * 16 + colc) * 8 + j0] = h;
    float hv = __bfloat162float(__builtin_bit_cast(__hip_bfloat16, h));
    float nb2 = hv * hv;
#pragma unroll
    for (int m = 32; m >= 1; m >>= 1) nb2 += __shfl_xor(nb2, m, 64);
    if ((t & 63) == 0) red[t >> 6] = nb2;
    __syncthreads();
    if (t == 0) {
        float n2 = 0.f;
#pragma unroll
        for (int j = 0; j < 16; ++j) n2 += red[j];
        scale[c] = (n2 > 0.f) ? (wptr[0] / sqrtf(n2)) : 0.f;
        actB[c] = (cnt > 0u) ? 1 : 0;
        countsF[c] = cnt;
    }
}

// ---- k3: cos GEMM + fused loss; NO atomics — per-block store to wsumArr
// (verbatim from round 9) ----
__global__ __launch_bounds__(256) void k3_loss(const unsigned short* __restrict__ xAfrag,
                                               const unsigned short* __restrict__ bfrag,
                                               const float* __restrict__ xn2g,
                                               const unsigned long long* __restrict__ masks,
                                               const unsigned char* __restrict__ actB,
                                               const float* __restrict__ scale,
                                               const float* __restrict__ bptr,
                                               float* __restrict__ wsumArr) {
    __shared__ float redsm[3][64][21];   // stride 21: conflict-free
    int t = threadIdx.x, wave = t >> 6, lane = t & 63;
    int q = lane >> 4, col = lane & 15;
    int rt = blockIdx.x;
    int rowbase = rt * 16;
    const uint4* A = (const uint4*)xAfrag + (size_t)rt * 32 * 64 + lane;
    const uint4* Bp = (const uint4*)bfrag + lane;
    int kb0 = wave * 8;

    float4v acc[5];
#pragma unroll
    for (int ct = 0; ct < 5; ++ct) acc[ct] = (float4v){0.f, 0.f, 0.f, 0.f};

    uint4 a[8];
#pragma unroll
    for (int j = 0; j < 8; ++j) a[j] = A[(size_t)(kb0 + j) * 64];
    uint4 b0[5], b1[5];
#pragma unroll
    for (int ct = 0; ct < 5; ++ct) b0[ct] = Bp[(size_t)(ct * 32 + kb0 + 0) * 64];
#pragma unroll
    for (int ct = 0; ct < 5; ++ct) b1[ct] = Bp[(size_t)(ct * 32 + kb0 + 1) * 64];

    for (int s = 0; s < 8; s += 2) {
        int p2 = s + 2 < 8 ? kb0 + s + 2 : kb0 + s;
        int p3 = s + 3 < 8 ? kb0 + s + 3 : kb0 + s + 1;
        {
            short8 af = __builtin_bit_cast(short8, a[s]);
#pragma unroll
            for (int ct = 0; ct < 5; ++ct) {
                short8 bf = __builtin_bit_cast(short8, b0[ct]);
                acc[ct] = __builtin_amdgcn_mfma_f32_16x16x32_bf16(af, bf, acc[ct], 0, 0, 0);
            }
#pragma unroll
            for (int ct = 0; ct < 5; ++ct) b0[ct] = Bp[(size_t)(ct * 32 + p2) * 64];
        }
        {
            short8 af = __builtin_bit_cast(short8, a[s + 1]);
#pragma unroll
            for (int ct = 0; ct < 5; ++ct) {
                short8 bf = __builtin_bit_cast(short8, b1[ct]);
                acc[ct] = __builtin_amdgcn_mfma_f32_16x16x32_bf16(af, bf, acc[ct], 0, 0, 0);
            }
#pragma unroll
            for (int ct = 0; ct < 5; ++ct) b1[ct] = Bp[(size_t)(ct * 32 + p3) * 64];
        }
    }

    if (wave) {
#pragma unroll
        for (int ct = 0; ct < 5; ++ct)
#pragma unroll
            for (int reg = 0; reg < 4; ++reg)
                redsm[wave - 1][lane][ct * 4 + reg] = acc[ct][reg];
    }
    __syncthreads();
    if (wave != 0) return;
#pragma unroll
    for (int w = 0; w < 3; ++w)
#pragma unroll
        for (int ct = 0; ct < 5; ++ct)
#pragma unroll
            for (int reg = 0; reg < 4; ++reg)
                acc[ct][reg] += redsm[w][lane][ct * 4 + reg];

    float bv = bptr[0];
    float sc[5]; unsigned char ab[5];
#pragma unroll
    for (int ct = 0; ct < 5; ++ct) { sc[ct] = scale[ct * 16 + col]; ab[ct] = actB[ct * 16 + col]; }

    float contrib = 0.f;
#pragma unroll
    for (int reg = 0; reg < 4; ++reg) {
        int rl = q * 4 + reg;
        int row = rowbase + rl;
        float inv = 1.0f / fmaxf(sqrtf(xn2g[row]), 1e-8f);
        unsigned long long mask = masks[row];
        float v[5]; float lmax = -1e30f;
#pragma unroll
        for (int ct = 0; ct < 5; ++ct) {
            float lg = acc[ct][reg] * sc[ct] * inv + bv;   // w*cos + b
            v[ct] = ab[ct] ? lg : -1e30f;
            lmax = fmaxf(lmax, v[ct]);
        }
#pragma unroll
        for (int m = 1; m < 16; m <<= 1) lmax = fmaxf(lmax, __shfl_xor(lmax, m, 16));
        float es = 0.f;
#pragma unroll
        for (int ct = 0; ct < 5; ++ct) es += __expf(v[ct] - lmax);
#pragma unroll
        for (int m = 1; m < 16; m <<= 1) es += __shfl_xor(es, m, 16);
        float lse = lmax + __logf(es);
        float ps = 0.f;
#pragma unroll
        for (int ct = 0; ct < 5; ++ct) {
            int c = ct * 16 + col;
            bool pos = (c < 64) ? (((mask >> c) & 1ull) != 0ull)
                                : ((c == 64) ? (mask == 0ull) : false);
            ps += pos ? v[ct] : 0.f;
        }
#pragma unroll
        for (int m = 1; m < 16; m <<= 1) ps += __shfl_xor(ps, m, 16);
        float npos = mask ? (float)__popcll(mask) : 1.0f;
        float crow = ps - npos * lse;
        if (col == 0) contrib += crow;
    }
#pragma unroll
    for (int m = 1; m < 64; m <<= 1) contrib += __shfl_xor(contrib, m, 64);
    if (lane == 0) wsumArr[rt] = contrib;    // plain coalesced store; no atomic
}

// ---- kE: reduce 1024 block partials + n_pairs -> loss ----
__global__ __launch_bounds__(256) void kE_final(const float* __restrict__ wsumArr,
                                                const unsigned* __restrict__ countsF,
                                                float* __restrict__ out) {
    __shared__ float red[4];
    int t = threadIdx.x, wave = t >> 6, lane = t & 63;
    float s = wsumArr[t] + wsumArr[t + 256] + wsumArr[t + 512] + wsumArr[t + 768];
#pragma unroll
    for (int m = 32; m >= 1; m >>= 1) s += __shfl_xor(s, m, 64);
    if (lane == 0) red[wave] = s;
    __syncthreads();
    if (t == 0) {
        float wv = red[0] + red[1] + red[2] + red[3];
        float np = 0.f;
        for (int c = 0; c < NC; ++c) np += (float)countsF[c];
        out[0] = -wv / np;
    }
}

extern "C" void kernel_launch(void* const* d_in, const int* in_sizes, int n_in,
                              void* d_out, int out_size, void* d_ws, size_t ws_size,
                              hipStream_t stream) {
    (void)in_sizes; (void)n_in; (void)out_size;
    const float* x = (const float*)d_in[0];
    const int* label = (const int*)d_in[1];
    const float* w = (const float*)d_in[2];
    const float* b = (const float*)d_in[3];

    char* ws = (char*)d_ws;
    float* scale = (float*)(ws + SCALE_B);
    unsigned char* actB = (unsigned char*)(ws + ACTB_B);
    unsigned* countsF = (unsigned*)(ws + CNTF_B);
    unsigned* cntpart = (unsigned*)(ws + CNTP_B);
    unsigned long long* masks = (unsigned long long*)(ws + MASK_B);
    float* xn2g = (float*)(ws + XN2_B);
    unsigned short* lfrag = (unsigned short*)(ws + LFRAG_B);
    unsigned short* bfrag = (unsigned short*)(ws + BFRAG_B);
    unsigned short* xAfrag = (unsigned short*)(ws + XAF_B);
    float* partial = (float*)(ws + PART_B);
    float* wsumArr = (float*)(ws + WARR_B);
    float* xn2p = (float*)(ws + XN2P_B);

    int kslices = 64;
    while (kslices > 8 && PART_B + (size_t)kslices * SLAB > WARR_B) kslices >>= 1;
    (void)ws_size;

    hipLaunchKernelGGL(kA_labels, dim3(256), dim3(256), 0, stream,
                       label, masks, cntpart, lfrag);
    hipLaunchKernelGGL(kG, dim3(16 * kslices), dim3(256), 0, stream,
                       x, lfrag, partial, xAfrag, xn2p, kslices);
    hipLaunchKernelGGL(kC_fuse, dim3(CPAD), dim3(1024), 0, stream,
                       w, cntpart, partial, kslices, bfrag, scale, actB, countsF, xn2p, xn2g);
    hipLaunchKernelGGL(k3_loss, dim3(NROWS / 16), dim3(256), 0, stream,
                       xAfrag, bfrag, xn2g, masks, actB, scale, b, wsumArr);
    hipLaunchKernelGGL(kE_final, dim3(1), dim3(256), 0, stream,
                       wsumArr, countsF, (float*)d_out);
}

// Round 11
// 145.543 us; speedup vs baseline: 1.2563x; 1.0092x over previous
//
#include <hip/hip_runtime.h>
#include <hip/hip_bf16.h>
#include <stdint.h>

#define NROWS 16384
#define NDIM  1024
#define NLAB  64
#define NC    65
#define CPAD  80

typedef float float4v __attribute__((ext_vector_type(4)));
typedef short short8  __attribute__((ext_vector_type(8)));

// ---- workspace layout (bytes); nothing needs pre-zeroing ----
static constexpr size_t SCALE_B = 0;         // 80 f32
static constexpr size_t ACTB_B  = 320;       // 80 u8
static constexpr size_t CNTF_B  = 448;       // 80 u32 counts
static constexpr size_t CNTP_B  = 1024;      // 256 x 80 u32 count slabs
static constexpr size_t MASK_B  = 83968;     // 16384 u64 row masks
static constexpr size_t XN2_B   = 215040;    // 16384 f32 row norms^2
static constexpr size_t LFRAG_B = 280576;    // labT bf16 A-frag (2.6 MB)
static constexpr size_t BFRAG_B = 2902016;   // unit anchors bf16 B-frag (160 KB)
static constexpr size_t XAF_B   = 3065856;   // x bf16 A-frag (32 MB)
static constexpr size_t PART_B  = 36620288;  // kslices*80*1024 f32 partials
static constexpr size_t SLAB    = (size_t)CPAD * NDIM * 4;
static constexpr size_t WARR_B  = 60000256;  // 1024 f32 per-block loss partials
static constexpr size_t XN2P_B  = 61000192;  // 16 x 16384 f32 xn2 partials (1 MB)

__device__ __forceinline__ unsigned short bf16u(float f) {
    __hip_bfloat16 h = __float2bfloat16(f);
    return __builtin_bit_cast(unsigned short, h);
}
__device__ __forceinline__ unsigned pk2(float a, float b) {
    return (unsigned)bf16u(a) | ((unsigned)bf16u(b) << 16);
}

// ---- kA: labels only; 256 blocks -> masks, cntpart, lfrag (verified) ----
__global__ __launch_bounds__(256) void kA_labels(const int* __restrict__ label,
                                                 unsigned long long* __restrict__ masks,
                                                 unsigned* __restrict__ cntpart,
                                                 unsigned short* __restrict__ lfrag) {
    __shared__ unsigned cnt[NC];
    __shared__ unsigned long long smask[64];
    int t = threadIdx.x;
    int bid = blockIdx.x;
    if (t < NC) cnt[t] = 0;
    __syncthreads();
    int wave = t >> 6, lane = t & 63;
    int rowblock = bid * 64;
    unsigned creg = 0, zreg = 0;
#pragma unroll 4
    for (int p = 0; p < 16; ++p) {
        int row = rowblock + p * 4 + wave;
        int v = label[row * NLAB + lane];
        unsigned long long m = __ballot(v != 0);
        creg += (unsigned)((m >> lane) & 1ull);
        if (lane == 0) {
            masks[row] = m;
            smask[p * 4 + wave] = m;
            zreg += (m == 0ull) ? 1u : 0u;
        }
    }
    atomicAdd(&cnt[lane], creg);
    if (lane == 0 && zreg) atomicAdd(&cnt[64], zreg);
    __syncthreads();
    if (t < 80) cntpart[bid * 80 + t] = (t < NC) ? cnt[t] : 0u;
    for (int pid = t; pid < 640; pid += 256) {
        int rt2l = pid / 320, rem = pid % 320;
        int ct = rem >> 6, ln = rem & 63;
        int qq = ln >> 4, cc = ln & 15;
        int c = ct * 16 + cc;
        int rbase = rt2l * 32 + qq * 8;
        unsigned pk[4];
#pragma unroll
        for (int jp = 0; jp < 4; ++jp) {
            unsigned long long m0 = smask[rbase + jp * 2], m1 = smask[rbase + jp * 2 + 1];
            unsigned b0, b1;
            if (c < 64)       { b0 = (unsigned)((m0 >> c) & 1ull); b1 = (unsigned)((m1 >> c) & 1ull); }
            else if (c == 64) { b0 = (m0 == 0ull); b1 = (m1 == 0ull); }
            else              { b0 = 0u; b1 = 0u; }
            pk[jp] = (b0 ? 0x3F80u : 0u) | (b1 ? 0x3F800000u : 0u);
        }
        uint4 w = make_uint4(pk[0], pk[1], pk[2], pk[3]);
        ((uint4*)lfrag)[((size_t)(bid * 2 + rt2l) * 5 + ct) * 64 + ln] = w;
    }
}

// ---- kG: anchor GEMM (labT @ x) + xAfrag emit + xn2 partials, all from the
// SAME LDS-staged f32 tile; TRIPLE-buffered staging (write tile i+1 at top of
// iter i, issue load of tile i+2 -> full-iteration HBM-latency hide window).
// x is read from HBM exactly once. grid = 16 * kslices ----
__global__ __launch_bounds__(256) void kG(const float* __restrict__ x,
                                          const unsigned short* __restrict__ lfrag,
                                          float* __restrict__ partial,
                                          unsigned short* __restrict__ xAfrag,
                                          float* __restrict__ xn2p,
                                          int kslices) {
    __shared__ float xt[3][32][65];
    __shared__ float sqacc[2][32][8];
    int t = threadIdx.x, wave = t >> 6, lane = t & 63;
    int q = lane >> 4, col = lane & 15;
    int dgroup = blockIdx.x & 15, ks = blockIdx.x >> 4;
    int nkb = (NROWS / kslices) >> 5;
    int kb0 = ks * nkb;
    int d = dgroup * 64 + wave * 16 + col;
    const uint4* A = (const uint4*)lfrag;
    int srow = t >> 3, sd = (t & 7) * 8;

    // emit-pass thread mapping
    int rh = t >> 7;              // row half of the 32-row tile
    int kbh = (t >> 6) & 1;       // 32-dim half of the 64-dim slice
    int qq = (t >> 4) & 3;
    int cc = t & 15;
    int r2 = rh * 16 + cc;        // LDS row
    int dch = kbh * 4 + qq;       // 8-dim chunk within the 64-dim slice

    float4v acc[5];
#pragma unroll
    for (int ct = 0; ct < 5; ++ct) acc[ct] = (float4v){0.f, 0.f, 0.f, 0.f};

    // prologue: tile 0 -> LDS[0]; tile 1 -> registers
    {
        const float* g = x + ((size_t)(kb0 * 32 + srow)) * NDIM + dgroup * 64 + sd;
        float4 u = *(const float4*)g, v2 = *(const float4*)(g + 4);
        float* L = &xt[0][srow][sd];
        L[0] = u.x; L[1] = u.y; L[2] = u.z; L[3] = u.w;
        L[4] = v2.x; L[5] = v2.y; L[6] = v2.z; L[7] = v2.w;
    }
    float4 ru, rv;
    if (nkb > 1) {
        const float* g = x + ((size_t)((kb0 + 1) * 32 + srow)) * NDIM + dgroup * 64 + sd;
        ru = *(const float4*)g; rv = *(const float4*)(g + 4);
    }
    __syncthreads();

    for (int i = 0; i < nkb; ++i) {
        int cur = i % 3;
        // write tile i+1 (held in regs since last iter) to its LDS slot
        if (i + 1 < nkb) {
            float* L = &xt[(i + 1) % 3][srow][sd];
            L[0] = ru.x; L[1] = ru.y; L[2] = ru.z; L[3] = ru.w;
            L[4] = rv.x; L[5] = rv.y; L[6] = rv.z; L[7] = rv.w;
        }
        // issue load of tile i+2 (full-iteration latency window)
        if (i + 2 < nkb) {
            const float* g = x + ((size_t)((kb0 + i + 2) * 32 + srow)) * NDIM + dgroup * 64 + sd;
            ru = *(const float4*)g; rv = *(const float4*)(g + 4);
        }
        // harvest previous iteration's xn2 partials (post-barrier safe)
        if (i > 0 && t < 32) {
            float s8 = 0.f;
#pragma unroll
            for (int d2 = 0; d2 < 8; ++d2) s8 += sqacc[(i - 1) & 1][t][d2];
            xn2p[(size_t)dgroup * NROWS + (size_t)(kb0 + i - 1) * 32 + t] = s8;
        }
        int kb = kb0 + i;
        uint4 a0[5];
#pragma unroll
        for (int ct = 0; ct < 5; ++ct) a0[ct] = A[((size_t)kb * 5 + ct) * 64 + lane];
        float f[8];
#pragma unroll
        for (int j = 0; j < 8; ++j) f[j] = xt[cur][q * 8 + j][wave * 16 + col];
        uint4 bq;
        bq.x = pk2(f[0], f[1]); bq.y = pk2(f[2], f[3]);
        bq.z = pk2(f[4], f[5]); bq.w = pk2(f[6], f[7]);
        short8 bf = __builtin_bit_cast(short8, bq);
#pragma unroll
        for (int ct = 0; ct < 5; ++ct) {
            short8 af = __builtin_bit_cast(short8, a0[ct]);
            acc[ct] = __builtin_amdgcn_mfma_f32_16x16x32_bf16(af, bf, acc[ct], 0, 0, 0);
        }
        // xAfrag emit + xn2 partial from the same LDS tile
        {
            float g0[8];
#pragma unroll
            for (int j = 0; j < 8; ++j) g0[j] = xt[cur][r2][dch * 8 + j];
            float sp = 0.f;
#pragma unroll
            for (int j = 0; j < 8; ++j) sp += g0[j] * g0[j];
            sqacc[i & 1][r2][dch] = sp;
            uint4 v;
            v.x = pk2(g0[0], g0[1]); v.y = pk2(g0[2], g0[3]);
            v.z = pk2(g0[4], g0[5]); v.w = pk2(g0[6], g0[7]);
            size_t slot = (((size_t)kb * 2 + rh) * 32 + dgroup * 2 + kbh) * 64 + (t & 63);
            ((uint4*)xAfrag)[slot] = v;
        }
        __syncthreads();
    }
    // final harvest
    if (t < 32) {
        float s8 = 0.f;
#pragma unroll
        for (int d2 = 0; d2 < 8; ++d2) s8 += sqacc[(nkb - 1) & 1][t][d2];
        xn2p[(size_t)dgroup * NROWS + (size_t)(kb0 + nkb - 1) * 32 + t] = s8;
    }
    float* pb = partial + (size_t)ks * CPAD * NDIM;
#pragma unroll
    for (int ct = 0; ct < 5; ++ct)
#pragma unroll
        for (int reg = 0; reg < 4; ++reg)
            pb[(size_t)(ct * 16 + q * 4 + reg) * NDIM + d] = acc[ct][reg];
}

// ---- kC: 80 blocks x 1024 thr; slice-reduce + counts + unit anchors + scale
// + xn2 partial reduce (idle-thread work) ----
__global__ __launch_bounds__(1024) void kC_fuse(const float* __restrict__ wptr,
                                                const unsigned* __restrict__ cntpart,
                                                const float* __restrict__ partial,
                                                int kslices,
                                                unsigned short* __restrict__ bfrag,
                                                float* __restrict__ scale,
                                                unsigned char* __restrict__ actB,
                                                unsigned* __restrict__ countsF,
                                                const float* __restrict__ xn2p,
                                                float* __restrict__ xn2g) {
    int c = blockIdx.x, t = threadIdx.x;
    __shared__ float red[16];
    __shared__ unsigned credu[4];
    __shared__ float bcast[1];
    if (t < 256) {
        unsigned cv = cntpart[t * 80 + c];
#pragma unroll
        for (int m = 32; m >= 1; m >>= 1) cv += __shfl_xor(cv, m, 64);
        if ((t & 63) == 0) credu[t >> 6] = cv;
    }
    // xn2 partial reduce: blocks 0..15 cover all 16384 rows
    int gid = c * 1024 + t;
    if (gid < NROWS) {
        float s2 = 0.f;
#pragma unroll
        for (int dg = 0; dg < 16; ++dg) s2 += xn2p[(size_t)dg * NROWS + gid];
        xn2g[gid] = s2;
    }
    const float* p = partial + (size_t)c * NDIM + t;
    float s = 0.f;
#pragma unroll 8
    for (int sl = 0; sl < kslices; ++sl) s += p[(size_t)sl * CPAD * NDIM];
    float ss = s * s;
#pragma unroll
    for (int m = 32; m >= 1; m >>= 1) ss += __shfl_xor(ss, m, 64);
    if ((t & 63) == 0) red[t >> 6] = ss;
    __syncthreads();
    if (t == 0) {
        float tot = 0.f;
#pragma unroll
        for (int j = 0; j < 16; ++j) tot += red[j];
        bcast[0] = sqrtf(tot);
    }
    unsigned cnt = credu[0] + credu[1] + credu[2] + credu[3];
    __syncthreads();
    float invc = 1.0f / (float)(cnt > 0u ? cnt : 1u);
    float a = s * invc;
    float an = fmaxf(bcast[0] * invc, 1e-8f);
    unsigned short h = bf16u(a / an);
    int ct = c >> 4, colc = c & 15;
    int kb = t >> 5, q = (t >> 3) & 3, j0 = t & 7;
    bfrag[((((size_t)ct * 32 + kb) * 64) + q * 16 + colc) * 8 + j0] = h;
    float hv = __bfloat162float(__builtin_bit_cast(__hip_bfloat16, h));
    float nb2 = hv * hv;
#pragma unroll
    for (int m = 32; m >= 1; m >>= 1) nb2 += __shfl_xor(nb2, m, 64);
    if ((t & 63) == 0) red[t >> 6] = nb2;
    __syncthreads();
    if (t == 0) {
        float n2 = 0.f;
#pragma unroll
        for (int j = 0; j < 16; ++j) n2 += red[j];
        scale[c] = (n2 > 0.f) ? (wptr[0] / sqrtf(n2)) : 0.f;
        actB[c] = (cnt > 0u) ? 1 : 0;
        countsF[c] = cnt;
    }
}

// ---- k3: cos GEMM + fused loss; NO atomics — per-block store to wsumArr
// (verbatim from round 9) ----
__global__ __launch_bounds__(256) void k3_loss(const unsigned short* __restrict__ xAfrag,
                                               const unsigned short* __restrict__ bfrag,
                                               const float* __restrict__ xn2g,
                                               const unsigned long long* __restrict__ masks,
                                               const unsigned char* __restrict__ actB,
                                               const float* __restrict__ scale,
                                               const float* __restrict__ bptr,
                                               float* __restrict__ wsumArr) {
    __shared__ float redsm[3][64][21];   // stride 21: conflict-free
    int t = threadIdx.x, wave = t >> 6, lane = t & 63;
    int q = lane >> 4, col = lane & 15;
    int rt = blockIdx.x;
    int rowbase = rt * 16;
    const uint4* A = (const uint4*)xAfrag + (size_t)rt * 32 * 64 + lane;
    const uint4* Bp = (const uint4*)bfrag + lane;
    int kb0 = wave * 8;

    float4v acc[5];
#pragma unroll
    for (int ct = 0; ct < 5; ++ct) acc[ct] = (float4v){0.f, 0.f, 0.f, 0.f};

    uint4 a[8];
#pragma unroll
    for (int j = 0; j < 8; ++j) a[j] = A[(size_t)(kb0 + j) * 64];
    uint4 b0[5], b1[5];
#pragma unroll
    for (int ct = 0; ct < 5; ++ct) b0[ct] = Bp[(size_t)(ct * 32 + kb0 + 0) * 64];
#pragma unroll
    for (int ct = 0; ct < 5; ++ct) b1[ct] = Bp[(size_t)(ct * 32 + kb0 + 1) * 64];

    for (int s = 0; s < 8; s += 2) {
        int p2 = s + 2 < 8 ? kb0 + s + 2 : kb0 + s;
        int p3 = s + 3 < 8 ? kb0 + s + 3 : kb0 + s + 1;
        {
            short8 af = __builtin_bit_cast(short8, a[s]);
#pragma unroll
            for (int ct = 0; ct < 5; ++ct) {
                short8 bf = __builtin_bit_cast(short8, b0[ct]);
                acc[ct] = __builtin_amdgcn_mfma_f32_16x16x32_bf16(af, bf, acc[ct], 0, 0, 0);
            }
#pragma unroll
            for (int ct = 0; ct < 5; ++ct) b0[ct] = Bp[(size_t)(ct * 32 + p2) * 64];
        }
        {
            short8 af = __builtin_bit_cast(short8, a[s + 1]);
#pragma unroll
            for (int ct = 0; ct < 5; ++ct) {
                short8 bf = __builtin_bit_cast(short8, b1[ct]);
                acc[ct] = __builtin_amdgcn_mfma_f32_16x16x32_bf16(af, bf, acc[ct], 0, 0, 0);
            }
#pragma unroll
            for (int ct = 0; ct < 5; ++ct) b1[ct] = Bp[(size_t)(ct * 32 + p3) * 64];
        }
    }

    if (wave) {
#pragma unroll
        for (int ct = 0; ct < 5; ++ct)
#pragma unroll
            for (int reg = 0; reg < 4; ++reg)
                redsm[wave - 1][lane][ct * 4 + reg] = acc[ct][reg];
    }
    __syncthreads();
    if (wave != 0) return;
#pragma unroll
    for (int w = 0; w < 3; ++w)
#pragma unroll
        for (int ct = 0; ct < 5; ++ct)
#pragma unroll
            for (int reg = 0; reg < 4; ++reg)
                acc[ct][reg] += redsm[w][lane][ct * 4 + reg];

    float bv = bptr[0];
    float sc[5]; unsigned char ab[5];
#pragma unroll
    for (int ct = 0; ct < 5; ++ct) { sc[ct] = scale[ct * 16 + col]; ab[ct] = actB[ct * 16 + col]; }

    float contrib = 0.f;
#pragma unroll
    for (int reg = 0; reg < 4; ++reg) {
        int rl = q * 4 + reg;
        int row = rowbase + rl;
        float inv = 1.0f / fmaxf(sqrtf(xn2g[row]), 1e-8f);
        unsigned long long mask = masks[row];
        float v[5]; float lmax = -1e30f;
#pragma unroll
        for (int ct = 0; ct < 5; ++ct) {
            float lg = acc[ct][reg] * sc[ct] * inv + bv;   // w*cos + b
            v[ct] = ab[ct] ? lg : -1e30f;
            lmax = fmaxf(lmax, v[ct]);
        }
#pragma unroll
        for (int m = 1; m < 16; m <<= 1) lmax = fmaxf(lmax, __shfl_xor(lmax, m, 16));
        float es = 0.f;
#pragma unroll
        for (int ct = 0; ct < 5; ++ct) es += __expf(v[ct] - lmax);
#pragma unroll
        for (int m = 1; m < 16; m <<= 1) es += __shfl_xor(es, m, 16);
        float lse = lmax + __logf(es);
        float ps = 0.f;
#pragma unroll
        for (int ct = 0; ct < 5; ++ct) {
            int c = ct * 16 + col;
            bool pos = (c < 64) ? (((mask >> c) & 1ull) != 0ull)
                                : ((c == 64) ? (mask == 0ull) : false);
            ps += pos ? v[ct] : 0.f;
        }
#pragma unroll
        for (int m = 1; m < 16; m <<= 1) ps += __shfl_xor(ps, m, 16);
        float npos = mask ? (float)__popcll(mask) : 1.0f;
        float crow = ps - npos * lse;
        if (col == 0) contrib += crow;
    }
#pragma unroll
    for (int m = 1; m < 64; m <<= 1) contrib += __shfl_xor(contrib, m, 64);
    if (lane == 0) wsumArr[rt] = contrib;    // plain coalesced store; no atomic
}

// ---- kE: reduce 1024 block partials + n_pairs -> loss ----
__global__ __launch_bounds__(256) void kE_final(const float* __restrict__ wsumArr,
                                                const unsigned* __restrict__ countsF,
                                                float* __restrict__ out) {
    __shared__ float red[4];
    int t = threadIdx.x, wave = t >> 6, lane = t & 63;
    float s = wsumArr[t] + wsumArr[t + 256] + wsumArr[t + 512] + wsumArr[t + 768];
#pragma unroll
    for (int m = 32; m >= 1; m >>= 1) s += __shfl_xor(s, m, 64);
    if (lane == 0) red[wave] = s;
    __syncthreads();
    if (t == 0) {
        float wv = red[0] + red[1] + red[2] + red[3];
        float np = 0.f;
        for (int c = 0; c < NC; ++c) np += (float)countsF[c];
        out[0] = -wv / np;
    }
}

extern "C" void kernel_launch(void* const* d_in, const int* in_sizes, int n_in,
                              void* d_out, int out_size, void* d_ws, size_t ws_size,
                              hipStream_t stream) {
    (void)in_sizes; (void)n_in; (void)out_size;
    const float* x = (const float*)d_in[0];
    const int* label = (const int*)d_in[1];
    const float* w = (const float*)d_in[2];
    const float* b = (const float*)d_in[3];

    char* ws = (char*)d_ws;
    float* scale = (float*)(ws + SCALE_B);
    unsigned char* actB = (unsigned char*)(ws + ACTB_B);
    unsigned* countsF = (unsigned*)(ws + CNTF_B);
    unsigned* cntpart = (unsigned*)(ws + CNTP_B);
    unsigned long long* masks = (unsigned long long*)(ws + MASK_B);
    float* xn2g = (float*)(ws + XN2_B);
    unsigned short* lfrag = (unsigned short*)(ws + LFRAG_B);
    unsigned short* bfrag = (unsigned short*)(ws + BFRAG_B);
    unsigned short* xAfrag = (unsigned short*)(ws + XAF_B);
    float* partial = (float*)(ws + PART_B);
    float* wsumArr = (float*)(ws + WARR_B);
    float* xn2p = (float*)(ws + XN2P_B);

    int kslices = 64;
    while (kslices > 8 && PART_B + (size_t)kslices * SLAB > WARR_B) kslices >>= 1;
    (void)ws_size;

    hipLaunchKernelGGL(kA_labels, dim3(256), dim3(256), 0, stream,
                       label, masks, cntpart, lfrag);
    hipLaunchKernelGGL(kG, dim3(16 * kslices), dim3(256), 0, stream,
                       x, lfrag, partial, xAfrag, xn2p, kslices);
    hipLaunchKernelGGL(kC_fuse, dim3(CPAD), dim3(1024), 0, stream,
                       w, cntpart, partial, kslices, bfrag, scale, actB, countsF, xn2p, xn2g);
    hipLaunchKernelGGL(k3_loss, dim3(NROWS / 16), dim3(256), 0, stream,
                       xAfrag, bfrag, xn2g, masks, actB, scale, b, wsumArr);
    hipLaunchKernelGGL(kE_final, dim3(1), dim3(256), 0, stream,
                       wsumArr, countsF, (float*)d_out);
}

// Round 12
// 143.084 us; speedup vs baseline: 1.2779x; 1.0172x over previous
//
#include <hip/hip_runtime.h>
#include <hip/hip_bf16.h>
#include <stdint.h>

#define NROWS 16384
#define NDIM  1024
#define NLAB  64
#define NC    65
#define CPAD  80

typedef float float4v __attribute__((ext_vector_type(4)));
typedef short short8  __attribute__((ext_vector_type(8)));

// ---- workspace layout (bytes); nothing needs pre-zeroing ----
static constexpr size_t SCALE_B = 0;         // 80 f32
static constexpr size_t ACTB_B  = 320;       // 80 u8
static constexpr size_t CNTF_B  = 448;       // 80 u32 counts
static constexpr size_t CNTP_B  = 1024;      // 256 x 80 u32 count slabs
static constexpr size_t MASK_B  = 83968;     // 16384 u64 row masks
static constexpr size_t XN2_B   = 215040;    // 16384 f32 row norms^2
static constexpr size_t LFRAG_B = 280576;    // labT bf16 A-frag (2.6 MB)
static constexpr size_t BFRAG_B = 2902016;   // unit anchors bf16 B-frag (160 KB)
static constexpr size_t XAF_B   = 3065856;   // x bf16 A-frag (32 MB)
static constexpr size_t PART_B  = 36620288;  // kslices*80*1024 bf16 partials (10.5 MB)
static constexpr size_t SLAB    = (size_t)CPAD * NDIM * 2;   // bf16 slab
static constexpr size_t WARR_B  = 60000256;  // 1024 f32 per-block loss partials
static constexpr size_t XN2P_B  = 61000192;  // 16 x 16384 f32 xn2 partials (1 MB)

__device__ __forceinline__ unsigned short bf16u(float f) {
    __hip_bfloat16 h = __float2bfloat16(f);
    return __builtin_bit_cast(unsigned short, h);
}
__device__ __forceinline__ unsigned pk2(float a, float b) {
    return (unsigned)bf16u(a) | ((unsigned)bf16u(b) << 16);
}

// ---- kA: labels only; 256 blocks -> masks, cntpart, lfrag (verified) ----
__global__ __launch_bounds__(256) void kA_labels(const int* __restrict__ label,
                                                 unsigned long long* __restrict__ masks,
                                                 unsigned* __restrict__ cntpart,
                                                 unsigned short* __restrict__ lfrag) {
    __shared__ unsigned cnt[NC];
    __shared__ unsigned long long smask[64];
    int t = threadIdx.x;
    int bid = blockIdx.x;
    if (t < NC) cnt[t] = 0;
    __syncthreads();
    int wave = t >> 6, lane = t & 63;
    int rowblock = bid * 64;
    unsigned creg = 0, zreg = 0;
#pragma unroll 4
    for (int p = 0; p < 16; ++p) {
        int row = rowblock + p * 4 + wave;
        int v = label[row * NLAB + lane];
        unsigned long long m = __ballot(v != 0);
        creg += (unsigned)((m >> lane) & 1ull);
        if (lane == 0) {
            masks[row] = m;
            smask[p * 4 + wave] = m;
            zreg += (m == 0ull) ? 1u : 0u;
        }
    }
    atomicAdd(&cnt[lane], creg);
    if (lane == 0 && zreg) atomicAdd(&cnt[64], zreg);
    __syncthreads();
    if (t < 80) cntpart[bid * 80 + t] = (t < NC) ? cnt[t] : 0u;
    for (int pid = t; pid < 640; pid += 256) {
        int rt2l = pid / 320, rem = pid % 320;
        int ct = rem >> 6, ln = rem & 63;
        int qq = ln >> 4, cc = ln & 15;
        int c = ct * 16 + cc;
        int rbase = rt2l * 32 + qq * 8;
        unsigned pk[4];
#pragma unroll
        for (int jp = 0; jp < 4; ++jp) {
            unsigned long long m0 = smask[rbase + jp * 2], m1 = smask[rbase + jp * 2 + 1];
            unsigned b0, b1;
            if (c < 64)       { b0 = (unsigned)((m0 >> c) & 1ull); b1 = (unsigned)((m1 >> c) & 1ull); }
            else if (c == 64) { b0 = (m0 == 0ull); b1 = (m1 == 0ull); }
            else              { b0 = 0u; b1 = 0u; }
            pk[jp] = (b0 ? 0x3F80u : 0u) | (b1 ? 0x3F800000u : 0u);
        }
        uint4 w = make_uint4(pk[0], pk[1], pk[2], pk[3]);
        ((uint4*)lfrag)[((size_t)(bid * 2 + rt2l) * 5 + ct) * 64 + ln] = w;
    }
}

// ---- kG: anchor GEMM (labT @ x) + xAfrag emit + xn2 partials, all from the
// SAME LDS-staged f32 tile; triple-buffered staging; bf16 partial store.
// x is read from HBM exactly once. grid = 16 * kslices ----
__global__ __launch_bounds__(256) void kG(const float* __restrict__ x,
                                          const unsigned short* __restrict__ lfrag,
                                          unsigned short* __restrict__ partial,
                                          unsigned short* __restrict__ xAfrag,
                                          float* __restrict__ xn2p,
                                          int kslices) {
    __shared__ float xt[3][32][65];
    __shared__ float sqacc[2][32][8];
    int t = threadIdx.x, wave = t >> 6, lane = t & 63;
    int q = lane >> 4, col = lane & 15;
    int dgroup = blockIdx.x & 15, ks = blockIdx.x >> 4;
    int nkb = (NROWS / kslices) >> 5;
    int kb0 = ks * nkb;
    int d = dgroup * 64 + wave * 16 + col;
    const uint4* A = (const uint4*)lfrag;
    int srow = t >> 3, sd = (t & 7) * 8;

    // emit-pass thread mapping
    int rh = t >> 7;              // row half of the 32-row tile
    int kbh = (t >> 6) & 1;       // 32-dim half of the 64-dim slice
    int qq = (t >> 4) & 3;
    int cc = t & 15;
    int r2 = rh * 16 + cc;        // LDS row
    int dch = kbh * 4 + qq;       // 8-dim chunk within the 64-dim slice

    float4v acc[5];
#pragma unroll
    for (int ct = 0; ct < 5; ++ct) acc[ct] = (float4v){0.f, 0.f, 0.f, 0.f};

    // prologue: tile 0 -> LDS[0]; tile 1 -> registers
    {
        const float* g = x + ((size_t)(kb0 * 32 + srow)) * NDIM + dgroup * 64 + sd;
        float4 u = *(const float4*)g, v2 = *(const float4*)(g + 4);
        float* L = &xt[0][srow][sd];
        L[0] = u.x; L[1] = u.y; L[2] = u.z; L[3] = u.w;
        L[4] = v2.x; L[5] = v2.y; L[6] = v2.z; L[7] = v2.w;
    }
    float4 ru, rv;
    if (nkb > 1) {
        const float* g = x + ((size_t)((kb0 + 1) * 32 + srow)) * NDIM + dgroup * 64 + sd;
        ru = *(const float4*)g; rv = *(const float4*)(g + 4);
    }
    __syncthreads();

    for (int i = 0; i < nkb; ++i) {
        int cur = i % 3;
        // write tile i+1 (held in regs since last iter) to its LDS slot
        if (i + 1 < nkb) {
            float* L = &xt[(i + 1) % 3][srow][sd];
            L[0] = ru.x; L[1] = ru.y; L[2] = ru.z; L[3] = ru.w;
            L[4] = rv.x; L[5] = rv.y; L[6] = rv.z; L[7] = rv.w;
        }
        // issue load of tile i+2 (full-iteration latency window)
        if (i + 2 < nkb) {
            const float* g = x + ((size_t)((kb0 + i + 2) * 32 + srow)) * NDIM + dgroup * 64 + sd;
            ru = *(const float4*)g; rv = *(const float4*)(g + 4);
        }
        // harvest previous iteration's xn2 partials (post-barrier safe)
        if (i > 0 && t < 32) {
            float s8 = 0.f;
#pragma unroll
            for (int d2 = 0; d2 < 8; ++d2) s8 += sqacc[(i - 1) & 1][t][d2];
            xn2p[(size_t)dgroup * NROWS + (size_t)(kb0 + i - 1) * 32 + t] = s8;
        }
        int kb = kb0 + i;
        uint4 a0[5];
#pragma unroll
        for (int ct = 0; ct < 5; ++ct) a0[ct] = A[((size_t)kb * 5 + ct) * 64 + lane];
        float f[8];
#pragma unroll
        for (int j = 0; j < 8; ++j) f[j] = xt[cur][q * 8 + j][wave * 16 + col];
        uint4 bq;
        bq.x = pk2(f[0], f[1]); bq.y = pk2(f[2], f[3]);
        bq.z = pk2(f[4], f[5]); bq.w = pk2(f[6], f[7]);
        short8 bf = __builtin_bit_cast(short8, bq);
#pragma unroll
        for (int ct = 0; ct < 5; ++ct) {
            short8 af = __builtin_bit_cast(short8, a0[ct]);
            acc[ct] = __builtin_amdgcn_mfma_f32_16x16x32_bf16(af, bf, acc[ct], 0, 0, 0);
        }
        // xAfrag emit + xn2 partial from the same LDS tile
        {
            float g0[8];
#pragma unroll
            for (int j = 0; j < 8; ++j) g0[j] = xt[cur][r2][dch * 8 + j];
            float sp = 0.f;
#pragma unroll
            for (int j = 0; j < 8; ++j) sp += g0[j] * g0[j];
            sqacc[i & 1][r2][dch] = sp;
            uint4 v;
            v.x = pk2(g0[0], g0[1]); v.y = pk2(g0[2], g0[3]);
            v.z = pk2(g0[4], g0[5]); v.w = pk2(g0[6], g0[7]);
            size_t slot = (((size_t)kb * 2 + rh) * 32 + dgroup * 2 + kbh) * 64 + (t & 63);
            ((uint4*)xAfrag)[slot] = v;
        }
        __syncthreads();
    }
    // final harvest
    if (t < 32) {
        float s8 = 0.f;
#pragma unroll
        for (int d2 = 0; d2 < 8; ++d2) s8 += sqacc[(nkb - 1) & 1][t][d2];
        xn2p[(size_t)dgroup * NROWS + (size_t)(kb0 + nkb - 1) * 32 + t] = s8;
    }
    unsigned short* pb = partial + (size_t)ks * CPAD * NDIM;
#pragma unroll
    for (int ct = 0; ct < 5; ++ct)
#pragma unroll
        for (int reg = 0; reg < 4; ++reg)
            pb[(size_t)(ct * 16 + q * 4 + reg) * NDIM + d] = bf16u(acc[ct][reg]);
}

// ---- kC: 80 blocks x 1024 thr; bf16 slice-reduce + counts + unit anchors
// + scale + xn2 partial reduce ----
__global__ __launch_bounds__(1024) void kC_fuse(const float* __restrict__ wptr,
                                                const unsigned* __restrict__ cntpart,
                                                const unsigned short* __restrict__ partial,
                                                int kslices,
                                                unsigned short* __restrict__ bfrag,
                                                float* __restrict__ scale,
                                                unsigned char* __restrict__ actB,
                                                unsigned* __restrict__ countsF,
                                                const float* __restrict__ xn2p,
                                                float* __restrict__ xn2g) {
    int c = blockIdx.x, t = threadIdx.x;
    __shared__ float red[16];
    __shared__ unsigned credu[4];
    __shared__ float bcast[1];
    if (t < 256) {
        unsigned cv = cntpart[t * 80 + c];
#pragma unroll
        for (int m = 32; m >= 1; m >>= 1) cv += __shfl_xor(cv, m, 64);
        if ((t & 63) == 0) credu[t >> 6] = cv;
    }
    // xn2 partial reduce: blocks 0..15 cover all 16384 rows
    int gid = c * 1024 + t;
    if (gid < NROWS) {
        float s2 = 0.f;
#pragma unroll
        for (int dg = 0; dg < 16; ++dg) s2 += xn2p[(size_t)dg * NROWS + gid];
        xn2g[gid] = s2;
    }
    const unsigned short* p = partial + (size_t)c * NDIM + t;
    float s = 0.f;
#pragma unroll 8
    for (int sl = 0; sl < kslices; ++sl) {
        unsigned short u = p[(size_t)sl * CPAD * NDIM];
        s += __builtin_bit_cast(float, (unsigned)u << 16);
    }
    float ss = s * s;
#pragma unroll
    for (int m = 32; m >= 1; m >>= 1) ss += __shfl_xor(ss, m, 64);
    if ((t & 63) == 0) red[t >> 6] = ss;
    __syncthreads();
    if (t == 0) {
        float tot = 0.f;
#pragma unroll
        for (int j = 0; j < 16; ++j) tot += red[j];
        bcast[0] = sqrtf(tot);
    }
    unsigned cnt = credu[0] + credu[1] + credu[2] + credu[3];
    __syncthreads();
    float invc = 1.0f / (float)(cnt > 0u ? cnt : 1u);
    float a = s * invc;
    float an = fmaxf(bcast[0] * invc, 1e-8f);
    unsigned short h = bf16u(a / an);
    int ct = c >> 4, colc = c & 15;
    int kb = t >> 5, q = (t >> 3) & 3, j0 = t & 7;
    bfrag[((((size_t)ct * 32 + kb) * 64) + q * 16 + colc) * 8 + j0] = h;
    float hv = __bfloat162float(__builtin_bit_cast(__hip_bfloat16, h));
    float nb2 = hv * hv;
#pragma unroll
    for (int m = 32; m >= 1; m >>= 1) nb2 += __shfl_xor(nb2, m, 64);
    if ((t & 63) == 0) red[t >> 6] = nb2;
    __syncthreads();
    if (t == 0) {
        float n2 = 0.f;
#pragma unroll
        for (int j = 0; j < 16; ++j) n2 += red[j];
        scale[c] = (n2 > 0.f) ? (wptr[0] / sqrtf(n2)) : 0.f;
        actB[c] = (cnt > 0u) ? 1 : 0;
        countsF[c] = cnt;
    }
}

// ---- k3: cos GEMM + fused loss; NO atomics — per-block store to wsumArr
// (verbatim from round 9) ----
__global__ __launch_bounds__(256) void k3_loss(const unsigned short* __restrict__ xAfrag,
                                               const unsigned short* __restrict__ bfrag,
                                               const float* __restrict__ xn2g,
                                               const unsigned long long* __restrict__ masks,
                                               const unsigned char* __restrict__ actB,
                                               const float* __restrict__ scale,
                                               const float* __restrict__ bptr,
                                               float* __restrict__ wsumArr) {
    __shared__ float redsm[3][64][21];   // stride 21: conflict-free
    int t = threadIdx.x, wave = t >> 6, lane = t & 63;
    int q = lane >> 4, col = lane & 15;
    int rt = blockIdx.x;
    int rowbase = rt * 16;
    const uint4* A = (const uint4*)xAfrag + (size_t)rt * 32 * 64 + lane;
    const uint4* Bp = (const uint4*)bfrag + lane;
    int kb0 = wave * 8;

    float4v acc[5];
#pragma unroll
    for (int ct = 0; ct < 5; ++ct) acc[ct] = (float4v){0.f, 0.f, 0.f, 0.f};

    uint4 a[8];
#pragma unroll
    for (int j = 0; j < 8; ++j) a[j] = A[(size_t)(kb0 + j) * 64];
    uint4 b0[5], b1[5];
#pragma unroll
    for (int ct = 0; ct < 5; ++ct) b0[ct] = Bp[(size_t)(ct * 32 + kb0 + 0) * 64];
#pragma unroll
    for (int ct = 0; ct < 5; ++ct) b1[ct] = Bp[(size_t)(ct * 32 + kb0 + 1) * 64];

    for (int s = 0; s < 8; s += 2) {
        int p2 = s + 2 < 8 ? kb0 + s + 2 : kb0 + s;
        int p3 = s + 3 < 8 ? kb0 + s + 3 : kb0 + s + 1;
        {
            short8 af = __builtin_bit_cast(short8, a[s]);
#pragma unroll
            for (int ct = 0; ct < 5; ++ct) {
                short8 bf = __builtin_bit_cast(short8, b0[ct]);
                acc[ct] = __builtin_amdgcn_mfma_f32_16x16x32_bf16(af, bf, acc[ct], 0, 0, 0);
            }
#pragma unroll
            for (int ct = 0; ct < 5; ++ct) b0[ct] = Bp[(size_t)(ct * 32 + p2) * 64];
        }
        {
            short8 af = __builtin_bit_cast(short8, a[s + 1]);
#pragma unroll
            for (int ct = 0; ct < 5; ++ct) {
                short8 bf = __builtin_bit_cast(short8, b1[ct]);
                acc[ct] = __builtin_amdgcn_mfma_f32_16x16x32_bf16(af, bf, acc[ct], 0, 0, 0);
            }
#pragma unroll
            for (int ct = 0; ct < 5; ++ct) b1[ct] = Bp[(size_t)(ct * 32 + p3) * 64];
        }
    }

    if (wave) {
#pragma unroll
        for (int ct = 0; ct < 5; ++ct)
#pragma unroll
            for (int reg = 0; reg < 4; ++reg)
                redsm[wave - 1][lane][ct * 4 + reg] = acc[ct][reg];
    }
    __syncthreads();
    if (wave != 0) return;
#pragma unroll
    for (int w = 0; w < 3; ++w)
#pragma unroll
        for (int ct = 0; ct < 5; ++ct)
#pragma unroll
            for (int reg = 0; reg < 4; ++reg)
                acc[ct][reg] += redsm[w][lane][ct * 4 + reg];

    float bv = bptr[0];
    float sc[5]; unsigned char ab[5];
#pragma unroll
    for (int ct = 0; ct < 5; ++ct) { sc[ct] = scale[ct * 16 + col]; ab[ct] = actB[ct * 16 + col]; }

    float contrib = 0.f;
#pragma unroll
    for (int reg = 0; reg < 4; ++reg) {
        int rl = q * 4 + reg;
        int row = rowbase + rl;
        float inv = 1.0f / fmaxf(sqrtf(xn2g[row]), 1e-8f);
        unsigned long long mask = masks[row];
        float v[5]; float lmax = -1e30f;
#pragma unroll
        for (int ct = 0; ct < 5; ++ct) {
            float lg = acc[ct][reg] * sc[ct] * inv + bv;   // w*cos + b
            v[ct] = ab[ct] ? lg : -1e30f;
            lmax = fmaxf(lmax, v[ct]);
        }
#pragma unroll
        for (int m = 1; m < 16; m <<= 1) lmax = fmaxf(lmax, __shfl_xor(lmax, m, 16));
        float es = 0.f;
#pragma unroll
        for (int ct = 0; ct < 5; ++ct) es += __expf(v[ct] - lmax);
#pragma unroll
        for (int m = 1; m < 16; m <<= 1) es += __shfl_xor(es, m, 16);
        float lse = lmax + __logf(es);
        float ps = 0.f;
#pragma unroll
        for (int ct = 0; ct < 5; ++ct) {
            int c = ct * 16 + col;
            bool pos = (c < 64) ? (((mask >> c) & 1ull) != 0ull)
                                : ((c == 64) ? (mask == 0ull) : false);
            ps += pos ? v[ct] : 0.f;
        }
#pragma unroll
        for (int m = 1; m < 16; m <<= 1) ps += __shfl_xor(ps, m, 16);
        float npos = mask ? (float)__popcll(mask) : 1.0f;
        float crow = ps - npos * lse;
        if (col == 0) contrib += crow;
    }
#pragma unroll
    for (int m = 1; m < 64; m <<= 1) contrib += __shfl_xor(contrib, m, 64);
    if (lane == 0) wsumArr[rt] = contrib;    // plain coalesced store; no atomic
}

// ---- kE: reduce 1024 block partials + n_pairs -> loss ----
__global__ __launch_bounds__(256) void kE_final(const float* __restrict__ wsumArr,
                                                const unsigned* __restrict__ countsF,
                                                float* __restrict__ out) {
    __shared__ float red[4];
    int t = threadIdx.x, wave = t >> 6, lane = t & 63;
    float s = wsumArr[t] + wsumArr[t + 256] + wsumArr[t + 512] + wsumArr[t + 768];
#pragma unroll
    for (int m = 32; m >= 1; m >>= 1) s += __shfl_xor(s, m, 64);
    if (lane == 0) red[wave] = s;
    __syncthreads();
    if (t == 0) {
        float wv = red[0] + red[1] + red[2] + red[3];
        float np = 0.f;
        for (int c = 0; c < NC; ++c) np += (float)countsF[c];
        out[0] = -wv / np;
    }
}

extern "C" void kernel_launch(void* const* d_in, const int* in_sizes, int n_in,
                              void* d_out, int out_size, void* d_ws, size_t ws_size,
                              hipStream_t stream) {
    (void)in_sizes; (void)n_in; (void)out_size;
    const float* x = (const float*)d_in[0];
    const int* label = (const int*)d_in[1];
    const float* w = (const float*)d_in[2];
    const float* b = (const float*)d_in[3];

    char* ws = (char*)d_ws;
    float* scale = (float*)(ws + SCALE_B);
    unsigned char* actB = (unsigned char*)(ws + ACTB_B);
    unsigned* countsF = (unsigned*)(ws + CNTF_B);
    unsigned* cntpart = (unsigned*)(ws + CNTP_B);
    unsigned long long* masks = (unsigned long long*)(ws + MASK_B);
    float* xn2g = (float*)(ws + XN2_B);
    unsigned short* lfrag = (unsigned short*)(ws + LFRAG_B);
    unsigned short* bfrag = (unsigned short*)(ws + BFRAG_B);
    unsigned short* xAfrag = (unsigned short*)(ws + XAF_B);
    unsigned short* partial = (unsigned short*)(ws + PART_B);
    float* wsumArr = (float*)(ws + WARR_B);
    float* xn2p = (float*)(ws + XN2P_B);

    int kslices = 64;
    while (kslices > 8 && PART_B + (size_t)kslices * SLAB > WARR_B) kslices >>= 1;
    (void)ws_size;

    hipLaunchKernelGGL(kA_labels, dim3(256), dim3(256), 0, stream,
                       label, masks, cntpart, lfrag);
    hipLaunchKernelGGL(kG, dim3(16 * kslices), dim3(256), 0, stream,
                       x, lfrag, partial, xAfrag, xn2p, kslices);
    hipLaunchKernelGGL(kC_fuse, dim3(CPAD), dim3(1024), 0, stream,
                       w, cntpart, partial, kslices, bfrag, scale, actB, countsF, xn2p, xn2g);
    hipLaunchKernelGGL(k3_loss, dim3(NROWS / 16), dim3(256), 0, stream,
                       xAfrag, bfrag, xn2g, masks, actB, scale, b, wsumArr);
    hipLaunchKernelGGL(kE_final, dim3(1), dim3(256), 0, stream,
                       wsumArr, countsF, (float*)d_out);
}